// Round 4
// baseline (608.852 us; speedup 1.0000x reference)
//
#include <hip/hip_runtime.h>
#include <hip/hip_bf16.h>
#include <stdint.h>

#define S_LEN 2048
#define HIDD  4096
#define NH    32
#define NKV   8
#define HD    128
#define NQKV  6144   // (NH + 2*NKV) * HD
#define ATT_SCALE 0.08838834764831845f
#define LOG2E 1.4426950408889634f

typedef unsigned short u16;
typedef __attribute__((ext_vector_type(8))) short short8;
typedef __attribute__((ext_vector_type(4))) float f32x4;

__device__ __forceinline__ unsigned f2bfbits(float f){
  union{float f; unsigned u;} v; v.f = f;
  return (v.u + 0x7FFFu + ((v.u>>16)&1u)) >> 16;
}
__device__ __forceinline__ unsigned packbf(float a, float b){
  return f2bfbits(a) | (f2bfbits(b)<<16);
}
// HW packed f32->bf16 (RTNE), 1 VALU op per pair (no builtin on gfx950; T12/m240)
__device__ __forceinline__ unsigned cvtpk(float lo, float hi){
  unsigned r;
  asm("v_cvt_pk_bf16_f32 %0, %1, %2" : "=v"(r) : "v"(lo), "v"(hi));
  return r;
}

#define GLOAD16(g, l) __builtin_amdgcn_global_load_lds( \
    (__attribute__((address_space(1))) void*)(g), \
    (__attribute__((address_space(3))) void*)(l), 16, 0, 0)

#define VMWAIT(n) asm volatile("s_waitcnt vmcnt(" #n ")" ::: "memory")

// ---------------- fp32 -> bf16 convert (8 elems/thread) ----------------
__global__ __launch_bounds__(256) void cvt_bf16(const float* __restrict__ in,
                                                u16* __restrict__ out, int n8){
  int i = blockIdx.x*256 + threadIdx.x;
  if (i >= n8) return;
  const float4* p = (const float4*)in;
  float4 a = p[2*i], b = p[2*i+1];
  union { unsigned u[4]; short8 s; } o;
  o.u[0] = packbf(a.x, a.y); o.u[1] = packbf(a.z, a.w);
  o.u[2] = packbf(b.x, b.y); o.u[3] = packbf(b.z, b.w);
  *(short8*)(out + (size_t)i*8) = o.s;
}

// ============ big-tile pipelined bf16 GEMM, C = A * B^T (fp32 C) ============
template<int BM>
__global__ __launch_bounds__(512) void gemm_bt_big(const u16* __restrict__ A,
                                                   const u16* __restrict__ B,
                                                   float* __restrict__ C,
                                                   int N, int K, int nbx){
  constexpr int MREP   = BM/32;
  constexpr int AH     = BM/128;
  constexpr int ABYTES = BM*64;
  __shared__ __align__(16) u16 Als[4*BM*32];
  __shared__ __align__(16) u16 Bls[4*256*32];

  const int tid = threadIdx.x;
  const int w = tid>>6, lane = tid&63, ln = lane&15, g = lane>>4;
  const int wm = w>>2, wn = w&3;
  const int swz5 = ((ln>>3)&1)<<5;

  const int nwg = gridDim.x;
  const int flat = blockIdx.x;
  const int wg = (flat&7)*(nwg>>3) + (flat>>3);
  const int by = wg / nbx;
  const int bx = wg - by*nbx;
  const int m0 = by*BM, n0 = bx*256;

  const int rs = ((tid>>6)<<4) + ((tid&63)>>2);
  const int ks = ((tid&3)<<3) ^ (((tid>>5)&1)<<4);
  const u16* srcA[AH];
  #pragma unroll
  for (int h=0; h<AH; h++) srcA[h] = A + (size_t)(m0 + h*128 + rs)*K + ks;
  const u16* srcB[2];
  #pragma unroll
  for (int h=0; h<2; h++) srcB[h] = B + (size_t)(n0 + h*128 + rs)*K + ks;
  char* Adst = (char*)Als + w*1024;
  char* Bdst = (char*)Bls + w*1024;

  const int NT = K>>5;

  #define STAGE_T(t) { const int bi_ = (t)&3; const int ko_ = (t)<<5;            \
    _Pragma("unroll")                                                            \
    for (int h=0;h<AH;h++) GLOAD16(srcA[h] + ko_, Adst + bi_*ABYTES + h*8192);   \
    _Pragma("unroll")                                                            \
    for (int h=0;h<2;h++)  GLOAD16(srcB[h] + ko_, Bdst + bi_*16384 + h*8192); }

  f32x4 acc[MREP][4];
  #pragma unroll
  for (int m=0;m<MREP;m++)
    #pragma unroll
    for (int n=0;n<4;n++) acc[m][n] = (f32x4){0.f,0.f,0.f,0.f};

  STAGE_T(0); STAGE_T(1); STAGE_T(2);

  auto compute_tile = [&](int bi){
    const char* Ab = (const char*)Als + bi*ABYTES;
    const char* Bb = (const char*)Bls + bi*16384;
    short8 bfr[4];
    #pragma unroll
    for (int n=0;n<4;n++)
      bfr[n] = *(const short8*)(Bb + (wn*4+n)*1024 + ln*64 + ((g*16)^swz5));
    short8 afr[4];
    #pragma unroll
    for (int m=0;m<4;m++)
      afr[m] = *(const short8*)(Ab + (wm*MREP+m)*1024 + ln*64 + ((g*16)^swz5));
    __builtin_amdgcn_s_setprio(1);
    #pragma unroll
    for (int m=0;m<4;m++)
      #pragma unroll
      for (int n=0;n<4;n++)
        acc[m][n] = __builtin_amdgcn_mfma_f32_16x16x32_bf16(afr[m], bfr[n], acc[m][n], 0,0,0);
    __builtin_amdgcn_s_setprio(0);
    if constexpr (BM==256){
      __builtin_amdgcn_s_barrier();
      short8 af2[4];
      #pragma unroll
      for (int m=0;m<4;m++)
        af2[m] = *(const short8*)(Ab + (wm*8+4+m)*1024 + ln*64 + ((g*16)^swz5));
      __builtin_amdgcn_s_setprio(1);
      #pragma unroll
      for (int m=0;m<4;m++)
        #pragma unroll
        for (int n=0;n<4;n++)
          acc[4+m][n] = __builtin_amdgcn_mfma_f32_16x16x32_bf16(af2[m], bfr[n], acc[4+m][n], 0,0,0);
      __builtin_amdgcn_s_setprio(0);
    }
    __builtin_amdgcn_s_barrier();
  };

  for (int T=0; T<NT-3; T++){
    STAGE_T(T+3);
    if constexpr (BM==256) VMWAIT(12); else VMWAIT(9);
    __builtin_amdgcn_s_barrier();
    compute_tile(T&3);
  }
  if constexpr (BM==256) VMWAIT(8); else VMWAIT(6);
  __builtin_amdgcn_s_barrier();
  compute_tile((NT-3)&3);
  if constexpr (BM==256) VMWAIT(4); else VMWAIT(3);
  __builtin_amdgcn_s_barrier();
  compute_tile((NT-2)&3);
  VMWAIT(0);
  __builtin_amdgcn_s_barrier();
  compute_tile((NT-1)&3);
  #undef STAGE_T

  #pragma unroll
  for (int m=0;m<MREP;m++)
    #pragma unroll
    for (int n=0;n<4;n++)
      #pragma unroll
      for (int r=0;r<4;r++){
        int row = m0 + wm*(BM/2) + m*16 + g*4 + r;
        int col = n0 + wn*64 + n*16 + ln;
        C[(size_t)row*N + col] = acc[m][n][r];
      }
}

// ---------------- RMSNorm + RoPE + layout (1 wave per (s, head-slot) row) -----
__global__ __launch_bounds__(256) void norm_rope(const float* __restrict__ QKV,
                                                 const float* __restrict__ cosb,
                                                 const float* __restrict__ sinb,
                                                 const float* __restrict__ qw,
                                                 const float* __restrict__ kw,
                                                 u16* __restrict__ Qn,
                                                 u16* __restrict__ Kn,
                                                 u16* __restrict__ Vt){
  int w = threadIdx.x>>6, lane = threadIdx.x&63;
  int row = blockIdx.x*4 + w;              // 0 .. S*48-1
  int s = row / 48, slot = row - s*48;
  const float* src = QKV + (size_t)s*NQKV + slot*HD;
  float x0 = src[lane], x1 = src[lane+64];
  if (slot < 40){
    float ss = x0*x0 + x1*x1;
    #pragma unroll
    for (int off=1; off<64; off<<=1) ss += __shfl_xor(ss, off, 64);
    float r = rsqrtf(ss*(1.0f/128.0f) + 1e-6f);
    const float* wgt = (slot < 32) ? qw : kw;
    float y0 = x0*r*wgt[lane], y1 = x1*r*wgt[lane+64];
    float c0 = cosb[(size_t)s*HD+lane], c1 = cosb[(size_t)s*HD+lane+64];
    float s0 = sinb[(size_t)s*HD+lane], s1 = sinb[(size_t)s*HD+lane+64];
    float o0 = y0*c0 - y1*s0;
    float o1 = y1*c1 + y0*s1;
    float sc = (slot < 32) ? ATT_SCALE : 1.0f;
    u16* dst = (slot < 32) ? (Qn + ((size_t)slot*S_LEN + s)*HD)
                           : (Kn + ((size_t)(slot-32)*S_LEN + s)*HD);
    dst[lane]    = (u16)f2bfbits(o0*sc);
    dst[lane+64] = (u16)f2bfbits(o1*sc);
  } else {
    int kvh = slot - 40;
    u16* dst = Vt + (size_t)kvh*HD*S_LEN + s;
    dst[(size_t)lane*S_LEN]      = (u16)f2bfbits(x0);
    dst[(size_t)(lane+64)*S_LEN] = (u16)f2bfbits(x1);
  }
}

// ---------------- flash attention v3 (causal, GQA) ----------------
// K staged in LDS (32KB dbuf, XOR-swizzled) -> 5 blocks/CU, 20 waves/CU.
// V read DIRECT from global (L2-resident, 512KB/head) - no Vs staging.
// Swapped operands: S^T = mfma(K, Q), lane-local softmax stats per q-row.
// defer-max (THR=8), cvt_pk P-packing, mask-free fast path off-diagonal.
__global__ __launch_bounds__(256) void flash_attn(const u16* __restrict__ Qn,
                                                  const u16* __restrict__ Kn,
                                                  const u16* __restrict__ Vt,
                                                  u16* __restrict__ O){
  __shared__ u16 Ks[2][64*128];   // [kv][d] swizzled, 16KB each

  const int h = blockIdx.y;
  const int qb = gridDim.x - 1 - blockIdx.x;   // big blocks first
  const int q0 = qb*64;
  const int w = threadIdx.x>>6, lane = threadIdx.x&63, ln = lane&15, g = lane>>4;
  const int kvh = h>>2;                        // NH/NKV = 4
  const int qrow = q0 + w*16 + ln;
  const u16* Qh = Qn + (size_t)h*S_LEN*HD;
  const u16* Kh = Kn + (size_t)kvh*S_LEN*HD;
  const u16* Vh = Vt + (size_t)kvh*HD*S_LEN;

  short8 qf[4];
  #pragma unroll
  for (int c=0;c<4;c++)
    qf[c] = *(const short8*)(Qh + (size_t)qrow*HD + c*32 + g*8);

  f32x4 ot[8];
  #pragma unroll
  for (int dt=0;dt<8;dt++) ot[dt] = (f32x4){0.f,0.f,0.f,0.f};
  float m_run = -1e30f, l_run = 0.f;

  const int nt = qb + 1;

  const int krow_w = w*4 + g;
  const int ksw    = ((krow_w)&7)<<4;
  const int kcol   = ((ln*16) ^ ksw) >> 1;

  #define STAGE(bufi, t) { \
    int kv0_ = (t)*64; \
    _Pragma("unroll") \
    for (int p=0;p<4;p++){ \
      const u16* ga = Kh + (size_t)(kv0_ + p*16 + krow_w)*HD + kcol; \
      GLOAD16(ga, (char*)&Ks[bufi][0] + p*4096 + w*1024); \
    } \
  }

  STAGE(0, 0);
  __syncthreads();

  for (int t=0; t<nt; ++t){
    const int cur = t&1;
    if (t+1 < nt) STAGE(cur^1, t+1);
    const int kv0 = t*64;

    // QK^T: S^T[kv][q] tiles, A = K from LDS, B = qf
    f32x4 st[4];
    #pragma unroll
    for (int mt=0; mt<4; mt++){
      f32x4 acc = (f32x4){0.f,0.f,0.f,0.f};
      #pragma unroll
      for (int c=0;c<4;c++){
        short8 kf = *(const short8*)((const char*)&Ks[cur][0]
                      + (mt*16+ln)*256 + ((c*64 + g*16) ^ ((ln&7)<<4)));
        acc = __builtin_amdgcn_mfma_f32_16x16x32_bf16(kf, qf[c], acc, 0,0,0);
      }
      st[mt] = acc;
    }

    // softmax (per-lane row stats, q = ln); only diagonal tile needs mask
    float p[4][4];
    float mtile = -1e30f;
    if (t < qb){   // kv0+63 < q0 <= qrow : no masking needed
      #pragma unroll
      for (int mt=0; mt<4; mt++)
        #pragma unroll
        for (int r=0;r<4;r++){
          p[mt][r] = st[mt][r];
          mtile = fmaxf(mtile, st[mt][r]);
        }
    } else {
      #pragma unroll
      for (int mt=0; mt<4; mt++)
        #pragma unroll
        for (int r=0;r<4;r++){
          int kv = kv0 + mt*16 + 4*g + r;
          float sv = (kv <= qrow) ? st[mt][r] : -1e30f;
          p[mt][r] = sv;
          mtile = fmaxf(mtile, sv);
        }
    }
    mtile = fmaxf(mtile, __shfl_xor(mtile, 16, 64));
    mtile = fmaxf(mtile, __shfl_xor(mtile, 32, 64));

    // defer-max (T13): skip rescale when max growth bounded
    bool defer = __all(mtile <= m_run + 8.0f);
    float m_new = defer ? m_run : fmaxf(m_run, mtile);

    float l_tile = 0.f;
    #pragma unroll
    for (int mt=0; mt<4; mt++)
      #pragma unroll
      for (int r=0;r<4;r++){
        float e = exp2f((p[mt][r] - m_new)*LOG2E);
        p[mt][r] = e;
        l_tile += e;
      }
    l_tile += __shfl_xor(l_tile, 16, 64);
    l_tile += __shfl_xor(l_tile, 32, 64);
    if (defer){
      l_run += l_tile;
    } else {
      float alpha = exp2f((m_run - m_new)*LOG2E);
      l_run = l_run*alpha + l_tile;
      m_run = m_new;
      #pragma unroll
      for (int dt=0;dt<8;dt++) ot[dt] *= alpha;
    }

    // P redistribution per 32-kv half (cvt_pk packing, shfl recipe)
    short8 pf[2];
    #pragma unroll
    for (int ks=0; ks<2; ks++){
      unsigned pk00 = cvtpk(p[2*ks  ][0], p[2*ks  ][1]);
      unsigned pk01 = cvtpk(p[2*ks  ][2], p[2*ks  ][3]);
      unsigned pk10 = cvtpk(p[2*ks+1][0], p[2*ks+1][1]);
      unsigned pk11 = cvtpk(p[2*ks+1][2], p[2*ks+1][3]);
      int src0 = (((2*g  )&3)<<4) | ln;
      int src1 = (((2*g+1)&3)<<4) | ln;
      unsigned t00 = (unsigned)__shfl((int)pk00, src0, 64);
      unsigned t10 = (unsigned)__shfl((int)pk10, src0, 64);
      unsigned t01 = (unsigned)__shfl((int)pk01, src0, 64);
      unsigned t11 = (unsigned)__shfl((int)pk11, src0, 64);
      unsigned u00 = (unsigned)__shfl((int)pk00, src1, 64);
      unsigned u10 = (unsigned)__shfl((int)pk10, src1, 64);
      unsigned u01 = (unsigned)__shfl((int)pk01, src1, 64);
      unsigned u11 = (unsigned)__shfl((int)pk11, src1, 64);
      bool hiv = (g >= 2);
      union { unsigned u[4]; short8 s; } pw;
      pw.u[0] = hiv ? t10 : t00;
      pw.u[1] = hiv ? t11 : t01;
      pw.u[2] = hiv ? u10 : u00;
      pw.u[3] = hiv ? u11 : u01;
      pf[ks] = pw.s;
    }

    // PV: O^T[d][q] += V^T chunks * P^T; V direct from global (L2-resident)
    #pragma unroll
    for (int dt=0;dt<8;dt++){
      #pragma unroll
      for (int ks=0; ks<2; ks++){
        short8 vf = *(const short8*)(Vh + (size_t)(dt*16+ln)*S_LEN + kv0 + ks*32 + g*8);
        ot[dt] = __builtin_amdgcn_mfma_f32_16x16x32_bf16(vf, pf[ks], ot[dt], 0,0,0);
      }
    }
    __syncthreads();
  }
  #undef STAGE

  float inv = 1.0f / l_run;
  u16* orow = O + (size_t)qrow*(NH*HD) + h*HD;
  #pragma unroll
  for (int dt=0;dt<8;dt++){
    #pragma unroll
    for (int rr=0; rr<4; rr+=2){
      unsigned pkd = cvtpk(ot[dt][rr]*inv, ot[dt][rr+1]*inv);
      *(unsigned*)(orow + dt*16 + g*4 + rr) = pkd;
    }
  }
}

// ---------------- host ----------------
extern "C" void kernel_launch(void* const* d_in, const int* in_sizes, int n_in,
                              void* d_out, int out_size, void* d_ws, size_t ws_size,
                              hipStream_t stream){
  (void)in_sizes; (void)n_in; (void)out_size; (void)ws_size;
  const float* hs   = (const float*)d_in[0];
  const float* cosb = (const float*)d_in[1];
  const float* sinb = (const float*)d_in[2];
  const float* Wq   = (const float*)d_in[3];
  const float* Wk   = (const float*)d_in[4];
  const float* Wv   = (const float*)d_in[5];
  const float* Wo   = (const float*)d_in[6];
  const float* qw   = (const float*)d_in[7];
  const float* kw   = (const float*)d_in[8];
  float* out = (float*)d_out;

  char* ws = (char*)d_ws;
  u16*   Xb    = (u16*)  (ws);
  u16*   WQKV  = (u16*)  (ws + 16777216);
  float* QKV   = (float*)(ws + 67108864);
  u16*   attnB = (u16*)  (ws + 67108864);   // overlay: QKV dead after norm_rope
  u16*   Qn    = (u16*)  (ws + 117440512);
  u16*   Kn    = (u16*)  (ws + 134217728);
  u16*   Vt    = (u16*)  (ws + 138412032);
  u16*   Wob   = WQKV;                      // overlay: WQKV dead after GEMM1

  cvt_bf16<<<(S_LEN*HIDD/8)/256, 256, 0, stream>>>(hs, Xb, S_LEN*HIDD/8);
  cvt_bf16<<<(NH*HD*HIDD/8)/256, 256, 0, stream>>>(Wq, WQKV, NH*HD*HIDD/8);
  cvt_bf16<<<(NKV*HD*HIDD/8)/256, 256, 0, stream>>>(Wk, WQKV + (size_t)NH*HD*HIDD, NKV*HD*HIDD/8);
  cvt_bf16<<<(NKV*HD*HIDD/8)/256, 256, 0, stream>>>(Wv, WQKV + (size_t)(NH+NKV)*HD*HIDD, NKV*HD*HIDD/8);
  // GEMM1: [2048 x 4096] x [6144 x 4096]^T
  gemm_bt_big<256><<<192, 512, 0, stream>>>(Xb, WQKV, QKV, NQKV, HIDD, NQKV/256);
  norm_rope<<<(S_LEN*48)/4, 256, 0, stream>>>(QKV, cosb, sinb, qw, kw, Qn, Kn, Vt);
  cvt_bf16<<<(HIDD*NH*HD/8)/256, 256, 0, stream>>>(Wo, Wob, HIDD*NH*HD/8);
  flash_attn<<<dim3(S_LEN/64, NH), 256, 0, stream>>>(Qn, Kn, Vt, attnB);
  // GEMM2: [2048 x 4096] x [4096 x 4096]^T
  gemm_bt_big<128><<<256, 512, 0, stream>>>(attnB, Wob, out, HIDD, HIDD, HIDD/256);
}

// Round 5
// 425.304 us; speedup vs baseline: 1.4316x; 1.4316x over previous
//
#include <hip/hip_runtime.h>
#include <hip/hip_bf16.h>
#include <stdint.h>

#define S_LEN 2048
#define HIDD  4096
#define NH    32
#define NKV   8
#define HD    128
#define NQKV  6144   // (NH + 2*NKV) * HD
#define ATT_SCALE 0.08838834764831845f
#define LOG2E 1.4426950408889634f

typedef unsigned short u16;
typedef __attribute__((ext_vector_type(8))) short short8;
typedef __attribute__((ext_vector_type(4))) float f32x4;

__device__ __forceinline__ unsigned f2bfbits(float f){
  union{float f; unsigned u;} v; v.f = f;
  return (v.u + 0x7FFFu + ((v.u>>16)&1u)) >> 16;
}
__device__ __forceinline__ unsigned packbf(float a, float b){
  return f2bfbits(a) | (f2bfbits(b)<<16);
}
// HW packed f32->bf16 (RTNE), 1 VALU op per pair
__device__ __forceinline__ unsigned cvtpk(float lo, float hi){
  unsigned r;
  asm("v_cvt_pk_bf16_f32 %0, %1, %2" : "=v"(r) : "v"(lo), "v"(hi));
  return r;
}

#define GLOAD16(g, l) __builtin_amdgcn_global_load_lds( \
    (__attribute__((address_space(1))) void*)(g), \
    (__attribute__((address_space(3))) void*)(l), 16, 0, 0)

#define VMWAIT(n) asm volatile("s_waitcnt vmcnt(" #n ")" ::: "memory")

// ---------------- fp32 -> bf16 convert (8 elems/thread) ----------------
__global__ __launch_bounds__(256) void cvt_bf16(const float* __restrict__ in,
                                                u16* __restrict__ out, int n8){
  int i = blockIdx.x*256 + threadIdx.x;
  if (i >= n8) return;
  const float4* p = (const float4*)in;
  float4 a = p[2*i], b = p[2*i+1];
  union { unsigned u[4]; short8 s; } o;
  o.u[0] = packbf(a.x, a.y); o.u[1] = packbf(a.z, a.w);
  o.u[2] = packbf(b.x, b.y); o.u[3] = packbf(b.z, b.w);
  *(short8*)(out + (size_t)i*8) = o.s;
}

// ============ big-tile pipelined bf16 GEMM, C = A * B^T (fp32 C) ============
template<int BM>
__global__ __launch_bounds__(512) void gemm_bt_big(const u16* __restrict__ A,
                                                   const u16* __restrict__ B,
                                                   float* __restrict__ C,
                                                   int N, int K, int nbx){
  constexpr int MREP   = BM/32;
  constexpr int AH     = BM/128;
  constexpr int ABYTES = BM*64;
  __shared__ __align__(16) u16 Als[4*BM*32];
  __shared__ __align__(16) u16 Bls[4*256*32];

  const int tid = threadIdx.x;
  const int w = tid>>6, lane = tid&63, ln = lane&15, g = lane>>4;
  const int wm = w>>2, wn = w&3;
  const int swz5 = ((ln>>3)&1)<<5;

  const int nwg = gridDim.x;
  const int flat = blockIdx.x;
  const int wg = (flat&7)*(nwg>>3) + (flat>>3);
  const int by = wg / nbx;
  const int bx = wg - by*nbx;
  const int m0 = by*BM, n0 = bx*256;

  const int rs = ((tid>>6)<<4) + ((tid&63)>>2);
  const int ks = ((tid&3)<<3) ^ (((tid>>5)&1)<<4);
  const u16* srcA[AH];
  #pragma unroll
  for (int h=0; h<AH; h++) srcA[h] = A + (size_t)(m0 + h*128 + rs)*K + ks;
  const u16* srcB[2];
  #pragma unroll
  for (int h=0; h<2; h++) srcB[h] = B + (size_t)(n0 + h*128 + rs)*K + ks;
  char* Adst = (char*)Als + w*1024;
  char* Bdst = (char*)Bls + w*1024;

  const int NT = K>>5;

  #define STAGE_T(t) { const int bi_ = (t)&3; const int ko_ = (t)<<5;            \
    _Pragma("unroll")                                                            \
    for (int h=0;h<AH;h++) GLOAD16(srcA[h] + ko_, Adst + bi_*ABYTES + h*8192);   \
    _Pragma("unroll")                                                            \
    for (int h=0;h<2;h++)  GLOAD16(srcB[h] + ko_, Bdst + bi_*16384 + h*8192); }

  f32x4 acc[MREP][4];
  #pragma unroll
  for (int m=0;m<MREP;m++)
    #pragma unroll
    for (int n=0;n<4;n++) acc[m][n] = (f32x4){0.f,0.f,0.f,0.f};

  STAGE_T(0); STAGE_T(1); STAGE_T(2);

  auto compute_tile = [&](int bi){
    const char* Ab = (const char*)Als + bi*ABYTES;
    const char* Bb = (const char*)Bls + bi*16384;
    short8 bfr[4];
    #pragma unroll
    for (int n=0;n<4;n++)
      bfr[n] = *(const short8*)(Bb + (wn*4+n)*1024 + ln*64 + ((g*16)^swz5));
    short8 afr[4];
    #pragma unroll
    for (int m=0;m<4;m++)
      afr[m] = *(const short8*)(Ab + (wm*MREP+m)*1024 + ln*64 + ((g*16)^swz5));
    __builtin_amdgcn_s_setprio(1);
    #pragma unroll
    for (int m=0;m<4;m++)
      #pragma unroll
      for (int n=0;n<4;n++)
        acc[m][n] = __builtin_amdgcn_mfma_f32_16x16x32_bf16(afr[m], bfr[n], acc[m][n], 0,0,0);
    __builtin_amdgcn_s_setprio(0);
    if constexpr (BM==256){
      __builtin_amdgcn_s_barrier();
      short8 af2[4];
      #pragma unroll
      for (int m=0;m<4;m++)
        af2[m] = *(const short8*)(Ab + (wm*8+4+m)*1024 + ln*64 + ((g*16)^swz5));
      __builtin_amdgcn_s_setprio(1);
      #pragma unroll
      for (int m=0;m<4;m++)
        #pragma unroll
        for (int n=0;n<4;n++)
          acc[4+m][n] = __builtin_amdgcn_mfma_f32_16x16x32_bf16(af2[m], bfr[n], acc[4+m][n], 0,0,0);
      __builtin_amdgcn_s_setprio(0);
    }
    __builtin_amdgcn_s_barrier();
  };

  for (int T=0; T<NT-3; T++){
    STAGE_T(T+3);
    if constexpr (BM==256) VMWAIT(12); else VMWAIT(9);
    __builtin_amdgcn_s_barrier();
    compute_tile(T&3);
  }
  if constexpr (BM==256) VMWAIT(8); else VMWAIT(6);
  __builtin_amdgcn_s_barrier();
  compute_tile((NT-3)&3);
  if constexpr (BM==256) VMWAIT(4); else VMWAIT(3);
  __builtin_amdgcn_s_barrier();
  compute_tile((NT-2)&3);
  VMWAIT(0);
  __builtin_amdgcn_s_barrier();
  compute_tile((NT-1)&3);
  #undef STAGE_T

  #pragma unroll
  for (int m=0;m<MREP;m++)
    #pragma unroll
    for (int n=0;n<4;n++)
      #pragma unroll
      for (int r=0;r<4;r++){
        int row = m0 + wm*(BM/2) + m*16 + g*4 + r;
        int col = n0 + wn*64 + n*16 + ln;
        C[(size_t)row*N + col] = acc[m][n][r];
      }
}

// ---------------- RMSNorm + RoPE + layout (1 wave per (s, head-slot) row) -----
__global__ __launch_bounds__(256) void norm_rope(const float* __restrict__ QKV,
                                                 const float* __restrict__ cosb,
                                                 const float* __restrict__ sinb,
                                                 const float* __restrict__ qw,
                                                 const float* __restrict__ kw,
                                                 u16* __restrict__ Qn,
                                                 u16* __restrict__ Kn,
                                                 u16* __restrict__ Vt){
  int w = threadIdx.x>>6, lane = threadIdx.x&63;
  int row = blockIdx.x*4 + w;              // 0 .. S*48-1
  int s = row / 48, slot = row - s*48;
  const float* src = QKV + (size_t)s*NQKV + slot*HD;
  float x0 = src[lane], x1 = src[lane+64];
  if (slot < 40){
    float ss = x0*x0 + x1*x1;
    #pragma unroll
    for (int off=1; off<64; off<<=1) ss += __shfl_xor(ss, off, 64);
    float r = rsqrtf(ss*(1.0f/128.0f) + 1e-6f);
    const float* wgt = (slot < 32) ? qw : kw;
    float y0 = x0*r*wgt[lane], y1 = x1*r*wgt[lane+64];
    float c0 = cosb[(size_t)s*HD+lane], c1 = cosb[(size_t)s*HD+lane+64];
    float s0 = sinb[(size_t)s*HD+lane], s1 = sinb[(size_t)s*HD+lane+64];
    float o0 = y0*c0 - y1*s0;
    float o1 = y1*c1 + y0*s1;
    float sc = (slot < 32) ? ATT_SCALE : 1.0f;
    u16* dst = (slot < 32) ? (Qn + ((size_t)slot*S_LEN + s)*HD)
                           : (Kn + ((size_t)(slot-32)*S_LEN + s)*HD);
    dst[lane]    = (u16)f2bfbits(o0*sc);
    dst[lane+64] = (u16)f2bfbits(o1*sc);
  } else {
    int kvh = slot - 40;
    u16* dst = Vt + (size_t)kvh*HD*S_LEN + s;
    dst[(size_t)lane*S_LEN]      = (u16)f2bfbits(x0);
    dst[(size_t)(lane+64)*S_LEN] = (u16)f2bfbits(x1);
  }
}

// ---------------- flash attention v4 (causal, GQA, balanced) ----------------
// K and V staged in LDS (64KB dbuf, XOR-swizzled, global_load_lds).
// Complementary pairing: block bx processes q-tiles {bx, 31-bx} sequentially
// -> every block does exactly 33 tile-units; grid 16x32 = 512 blocks = exactly
// 2 resident blocks/CU (steady 8 waves/CU, no tail).
// Swapped operands: S^T = mfma(K, Q), lane-local softmax stats per q-row.
// defer-max (THR=8), cvt_pk P-packing, mask only on diagonal tile.
__global__ __launch_bounds__(256) void flash_attn(const u16* __restrict__ Qn,
                                                  const u16* __restrict__ Kn,
                                                  const u16* __restrict__ Vt,
                                                  u16* __restrict__ O){
  __shared__ u16 Ks[2][64*128];   // [kv][d] swizzled, 16KB each
  __shared__ u16 Vs[2][128*64];   // [d][kv] swizzled, 16KB each

  const int h = blockIdx.y;
  const int w = threadIdx.x>>6, lane = threadIdx.x&63, ln = lane&15, g = lane>>4;
  const int kvh = h>>2;                        // NH/NKV = 4
  const u16* Qh = Qn + (size_t)h*S_LEN*HD;
  const u16* Kh = Kn + (size_t)kvh*S_LEN*HD;
  const u16* Vh = Vt + (size_t)kvh*HD*S_LEN;

  const int krow_w = w*4 + g;
  const int ksw    = ((krow_w)&7)<<4;
  const int kcol   = ((ln*16) ^ ksw) >> 1;
  const int vrow_w = w*8 + (lane>>3);
  const int vsw    = ((lane>>3)&7)<<4;
  const int vcol   = (((lane&7)*16) ^ vsw) >> 1;

  #define STAGE(bufi, t) { \
    int kv0_ = (t)*64; \
    _Pragma("unroll") \
    for (int p=0;p<4;p++){ \
      const u16* ga = Kh + (size_t)(kv0_ + p*16 + krow_w)*HD + kcol; \
      GLOAD16(ga, (char*)&Ks[bufi][0] + p*4096 + w*1024); \
      const u16* gv = Vh + (size_t)(p*32 + vrow_w)*S_LEN + kv0_ + vcol; \
      GLOAD16(gv, (char*)&Vs[bufi][0] + p*4096 + w*1024); \
    } \
  }

  #pragma unroll 1
  for (int ph=0; ph<2; ph++){
    const int qb = ph ? (31 - blockIdx.x) : blockIdx.x;
    const int q0 = qb*64;
    const int qrow = q0 + w*16 + ln;

    short8 qf[4];
    #pragma unroll
    for (int c=0;c<4;c++)
      qf[c] = *(const short8*)(Qh + (size_t)qrow*HD + c*32 + g*8);

    f32x4 ot[8];
    #pragma unroll
    for (int dt=0;dt<8;dt++) ot[dt] = (f32x4){0.f,0.f,0.f,0.f};
    float m_run = -1e30f, l_run = 0.f;

    const int nt = qb + 1;

    STAGE(0, 0);
    __syncthreads();

    for (int t=0; t<nt; ++t){
      const int cur = t&1;
      if (t+1 < nt) STAGE(cur^1, t+1);
      const int kv0 = t*64;

      // QK^T: S^T[kv][q] tiles, A = K from LDS, B = qf
      f32x4 st[4];
      #pragma unroll
      for (int mt=0; mt<4; mt++){
        f32x4 acc = (f32x4){0.f,0.f,0.f,0.f};
        #pragma unroll
        for (int c=0;c<4;c++){
          short8 kf = *(const short8*)((const char*)&Ks[cur][0]
                        + (mt*16+ln)*256 + ((c*64 + g*16) ^ ((ln&7)<<4)));
          acc = __builtin_amdgcn_mfma_f32_16x16x32_bf16(kf, qf[c], acc, 0,0,0);
        }
        st[mt] = acc;
      }

      // softmax (per-lane row stats, q = ln); only diagonal tile needs mask
      float p[4][4];
      float mtile = -1e30f;
      if (t < qb){
        #pragma unroll
        for (int mt=0; mt<4; mt++)
          #pragma unroll
          for (int r=0;r<4;r++){
            p[mt][r] = st[mt][r];
            mtile = fmaxf(mtile, st[mt][r]);
          }
      } else {
        #pragma unroll
        for (int mt=0; mt<4; mt++)
          #pragma unroll
          for (int r=0;r<4;r++){
            int kv = kv0 + mt*16 + 4*g + r;
            float sv = (kv <= qrow) ? st[mt][r] : -1e30f;
            p[mt][r] = sv;
            mtile = fmaxf(mtile, sv);
          }
      }
      mtile = fmaxf(mtile, __shfl_xor(mtile, 16, 64));
      mtile = fmaxf(mtile, __shfl_xor(mtile, 32, 64));

      bool defer = __all(mtile <= m_run + 8.0f);
      float m_new = defer ? m_run : fmaxf(m_run, mtile);

      float l_tile = 0.f;
      #pragma unroll
      for (int mt=0; mt<4; mt++)
        #pragma unroll
        for (int r=0;r<4;r++){
          float e = exp2f((p[mt][r] - m_new)*LOG2E);
          p[mt][r] = e;
          l_tile += e;
        }
      l_tile += __shfl_xor(l_tile, 16, 64);
      l_tile += __shfl_xor(l_tile, 32, 64);
      if (defer){
        l_run += l_tile;
      } else {
        float alpha = exp2f((m_run - m_new)*LOG2E);
        l_run = l_run*alpha + l_tile;
        m_run = m_new;
        #pragma unroll
        for (int dt=0;dt<8;dt++) ot[dt] *= alpha;
      }

      // P redistribution per 32-kv half (cvt_pk packing, shfl recipe)
      short8 pf[2];
      #pragma unroll
      for (int ks2=0; ks2<2; ks2++){
        unsigned pk00 = cvtpk(p[2*ks2  ][0], p[2*ks2  ][1]);
        unsigned pk01 = cvtpk(p[2*ks2  ][2], p[2*ks2  ][3]);
        unsigned pk10 = cvtpk(p[2*ks2+1][0], p[2*ks2+1][1]);
        unsigned pk11 = cvtpk(p[2*ks2+1][2], p[2*ks2+1][3]);
        int src0 = (((2*g  )&3)<<4) | ln;
        int src1 = (((2*g+1)&3)<<4) | ln;
        unsigned t00 = (unsigned)__shfl((int)pk00, src0, 64);
        unsigned t10 = (unsigned)__shfl((int)pk10, src0, 64);
        unsigned t01 = (unsigned)__shfl((int)pk01, src0, 64);
        unsigned t11 = (unsigned)__shfl((int)pk11, src0, 64);
        unsigned u00 = (unsigned)__shfl((int)pk00, src1, 64);
        unsigned u10 = (unsigned)__shfl((int)pk10, src1, 64);
        unsigned u01 = (unsigned)__shfl((int)pk01, src1, 64);
        unsigned u11 = (unsigned)__shfl((int)pk11, src1, 64);
        bool hiv = (g >= 2);
        union { unsigned u[4]; short8 s; } pw;
        pw.u[0] = hiv ? t10 : t00;
        pw.u[1] = hiv ? t11 : t01;
        pw.u[2] = hiv ? u10 : u00;
        pw.u[3] = hiv ? u11 : u01;
        pf[ks2] = pw.s;
      }

      // PV: O^T[d][q] += V^T chunks * P^T, A = V from LDS
      #pragma unroll
      for (int dt=0;dt<8;dt++){
        #pragma unroll
        for (int ks2=0; ks2<2; ks2++){
          short8 vf = *(const short8*)((const char*)&Vs[cur][0]
                        + (dt*16+ln)*128 + ((ks2*64 + g*16) ^ ((ln&7)<<4)));
          ot[dt] = __builtin_amdgcn_mfma_f32_16x16x32_bf16(vf, pf[ks2], ot[dt], 0,0,0);
        }
      }
      __syncthreads();
    }

    float inv = 1.0f / l_run;
    u16* orow = O + (size_t)qrow*(NH*HD) + h*HD;
    #pragma unroll
    for (int dt=0;dt<8;dt++){
      #pragma unroll
      for (int rr=0; rr<4; rr+=2){
        unsigned pkd = cvtpk(ot[dt][rr]*inv, ot[dt][rr+1]*inv);
        *(unsigned*)(orow + dt*16 + g*4 + rr) = pkd;
      }
    }
  }
  #undef STAGE
}

// ---------------- host ----------------
extern "C" void kernel_launch(void* const* d_in, const int* in_sizes, int n_in,
                              void* d_out, int out_size, void* d_ws, size_t ws_size,
                              hipStream_t stream){
  (void)in_sizes; (void)n_in; (void)out_size; (void)ws_size;
  const float* hs   = (const float*)d_in[0];
  const float* cosb = (const float*)d_in[1];
  const float* sinb = (const float*)d_in[2];
  const float* Wq   = (const float*)d_in[3];
  const float* Wk   = (const float*)d_in[4];
  const float* Wv   = (const float*)d_in[5];
  const float* Wo   = (const float*)d_in[6];
  const float* qw   = (const float*)d_in[7];
  const float* kw   = (const float*)d_in[8];
  float* out = (float*)d_out;

  char* ws = (char*)d_ws;
  u16*   Xb    = (u16*)  (ws);
  u16*   WQKV  = (u16*)  (ws + 16777216);
  float* QKV   = (float*)(ws + 67108864);
  u16*   attnB = (u16*)  (ws + 67108864);   // overlay: QKV dead after norm_rope
  u16*   Qn    = (u16*)  (ws + 117440512);
  u16*   Kn    = (u16*)  (ws + 134217728);
  u16*   Vt    = (u16*)  (ws + 138412032);
  u16*   Wob   = WQKV;                      // overlay: WQKV dead after GEMM1

  cvt_bf16<<<(S_LEN*HIDD/8)/256, 256, 0, stream>>>(hs, Xb, S_LEN*HIDD/8);
  cvt_bf16<<<(NH*HD*HIDD/8)/256, 256, 0, stream>>>(Wq, WQKV, NH*HD*HIDD/8);
  cvt_bf16<<<(NKV*HD*HIDD/8)/256, 256, 0, stream>>>(Wk, WQKV + (size_t)NH*HD*HIDD, NKV*HD*HIDD/8);
  cvt_bf16<<<(NKV*HD*HIDD/8)/256, 256, 0, stream>>>(Wv, WQKV + (size_t)(NH+NKV)*HD*HIDD, NKV*HD*HIDD/8);
  // GEMM1: [2048 x 4096] x [6144 x 4096]^T
  gemm_bt_big<256><<<192, 512, 0, stream>>>(Xb, WQKV, QKV, NQKV, HIDD, NQKV/256);
  norm_rope<<<(S_LEN*48)/4, 256, 0, stream>>>(QKV, cosb, sinb, qw, kw, Qn, Kn, Vt);
  cvt_bf16<<<(HIDD*NH*HD/8)/256, 256, 0, stream>>>(Wo, Wob, HIDD*NH*HD/8);
  // flash attention: 16 complementary pairs x 32 heads = 512 blocks
  flash_attn<<<dim3(16, NH), 256, 0, stream>>>(Qn, Kn, Vt, attnB);
  // GEMM2: [2048 x 4096] x [4096 x 4096]^T
  gemm_bt_big<128><<<256, 512, 0, stream>>>(attnB, Wob, out, HIDD, HIDD, HIDD/256);
}

// Round 6
// 423.345 us; speedup vs baseline: 1.4382x; 1.0046x over previous
//
#include <hip/hip_runtime.h>
#include <hip/hip_bf16.h>
#include <stdint.h>

#define S_LEN 2048
#define HIDD  4096
#define NH    32
#define NKV   8
#define HD    128
#define NQKV  6144   // (NH + 2*NKV) * HD
#define ATT_SCALE 0.08838834764831845f
#define LOG2E 1.4426950408889634f

typedef unsigned short u16;
typedef __attribute__((ext_vector_type(8))) short short8;
typedef __attribute__((ext_vector_type(4))) float f32x4;

__device__ __forceinline__ unsigned f2bfbits(float f){
  union{float f; unsigned u;} v; v.f = f;
  return (v.u + 0x7FFFu + ((v.u>>16)&1u)) >> 16;
}
__device__ __forceinline__ unsigned packbf(float a, float b){
  return f2bfbits(a) | (f2bfbits(b)<<16);
}
// HW packed f32->bf16 (RTNE), 1 VALU op per pair
__device__ __forceinline__ unsigned cvtpk(float lo, float hi){
  unsigned r;
  asm("v_cvt_pk_bf16_f32 %0, %1, %2" : "=v"(r) : "v"(lo), "v"(hi));
  return r;
}

#define GLOAD16(g, l) __builtin_amdgcn_global_load_lds( \
    (__attribute__((address_space(1))) void*)(g), \
    (__attribute__((address_space(3))) void*)(l), 16, 0, 0)

#define VMWAIT(n) asm volatile("s_waitcnt vmcnt(" #n ")" ::: "memory")

// ---------------- fp32 -> bf16 convert (8 elems/thread) ----------------
__global__ __launch_bounds__(256) void cvt_bf16(const float* __restrict__ in,
                                                u16* __restrict__ out, int n8){
  int i = blockIdx.x*256 + threadIdx.x;
  if (i >= n8) return;
  const float4* p = (const float4*)in;
  float4 a = p[2*i], b = p[2*i+1];
  union { unsigned u[4]; short8 s; } o;
  o.u[0] = packbf(a.x, a.y); o.u[1] = packbf(a.z, a.w);
  o.u[2] = packbf(b.x, b.y); o.u[3] = packbf(b.z, b.w);
  *(short8*)(out + (size_t)i*8) = o.s;
}

// ============ big-tile pipelined bf16 GEMM, C = A * B^T (fp32 C) ============
// BM x 256 tile, BK=32, 8 waves (2M x 4N), 4-deep circular LDS buffer.
// ONE barrier per K-tile; prefetch distance 2; counted vmcnt (4 loads/stage
// for BM=256, 3 for BM=128) - pipeline never drains until the peeled last
// iteration. Race-safety: stage target (T+2)&3 is >=2 buffers away from any
// buffer readable by a wave within one barrier of this one.
template<int BM>
__global__ __launch_bounds__(512) void gemm_bt_big(const u16* __restrict__ A,
                                                   const u16* __restrict__ B,
                                                   float* __restrict__ C,
                                                   int N, int K, int nbx){
  constexpr int MREP   = BM/32;
  constexpr int AH     = BM/128;
  constexpr int ABYTES = BM*64;
  __shared__ __align__(16) u16 Als[4*BM*32];
  __shared__ __align__(16) u16 Bls[4*256*32];

  const int tid = threadIdx.x;
  const int w = tid>>6, lane = tid&63, ln = lane&15, g = lane>>4;
  const int wm = w>>2, wn = w&3;
  const int swz5 = ((ln>>3)&1)<<5;

  const int nwg = gridDim.x;
  const int flat = blockIdx.x;
  const int wg = (flat&7)*(nwg>>3) + (flat>>3);
  const int by = wg / nbx;
  const int bx = wg - by*nbx;
  const int m0 = by*BM, n0 = bx*256;

  const int rs = ((tid>>6)<<4) + ((tid&63)>>2);
  const int ks = ((tid&3)<<3) ^ (((tid>>5)&1)<<4);
  const u16* srcA[AH];
  #pragma unroll
  for (int h=0; h<AH; h++) srcA[h] = A + (size_t)(m0 + h*128 + rs)*K + ks;
  const u16* srcB[2];
  #pragma unroll
  for (int h=0; h<2; h++) srcB[h] = B + (size_t)(n0 + h*128 + rs)*K + ks;
  char* Adst = (char*)Als + w*1024;
  char* Bdst = (char*)Bls + w*1024;

  const int NT = K>>5;

  #define STAGE_T(t) { const int bi_ = (t)&3; const int ko_ = (t)<<5;            \
    _Pragma("unroll")                                                            \
    for (int h=0;h<AH;h++) GLOAD16(srcA[h] + ko_, Adst + bi_*ABYTES + h*8192);   \
    _Pragma("unroll")                                                            \
    for (int h=0;h<2;h++)  GLOAD16(srcB[h] + ko_, Bdst + bi_*16384 + h*8192); }

  f32x4 acc[MREP][4];
  #pragma unroll
  for (int m=0;m<MREP;m++)
    #pragma unroll
    for (int n=0;n<4;n++) acc[m][n] = (f32x4){0.f,0.f,0.f,0.f};

  STAGE_T(0); STAGE_T(1);

  auto compute_tile = [&](int bi){
    const char* Ab = (const char*)Als + bi*ABYTES;
    const char* Bb = (const char*)Bls + bi*16384;
    short8 bfr[4];
    #pragma unroll
    for (int n=0;n<4;n++)
      bfr[n] = *(const short8*)(Bb + (wn*4+n)*1024 + ln*64 + ((g*16)^swz5));
    short8 afr[4];
    #pragma unroll
    for (int m=0;m<4;m++)
      afr[m] = *(const short8*)(Ab + (wm*MREP+m)*1024 + ln*64 + ((g*16)^swz5));
    __builtin_amdgcn_s_setprio(1);
    #pragma unroll
    for (int m=0;m<4;m++)
      #pragma unroll
      for (int n=0;n<4;n++)
        acc[m][n] = __builtin_amdgcn_mfma_f32_16x16x32_bf16(afr[m], bfr[n], acc[m][n], 0,0,0);
    __builtin_amdgcn_s_setprio(0);
    if constexpr (BM==256){
      short8 af2[4];
      #pragma unroll
      for (int m=0;m<4;m++)
        af2[m] = *(const short8*)(Ab + (wm*8+4+m)*1024 + ln*64 + ((g*16)^swz5));
      __builtin_amdgcn_s_setprio(1);
      #pragma unroll
      for (int m=0;m<4;m++)
        #pragma unroll
        for (int n=0;n<4;n++)
          acc[4+m][n] = __builtin_amdgcn_mfma_f32_16x16x32_bf16(af2[m], bfr[n], acc[4+m][n], 0,0,0);
      __builtin_amdgcn_s_setprio(0);
    }
  };

  // main loop: one barrier per K-tile, counted vmcnt, stage distance 2
  for (int T=0; T<NT-1; T++){
    if constexpr (BM==256) VMWAIT(4); else VMWAIT(3);
    __builtin_amdgcn_s_barrier();
    if (T+2 < NT) STAGE_T(T+2);
    compute_tile(T&3);
  }
  // peeled last iteration: full drain
  VMWAIT(0);
  __builtin_amdgcn_s_barrier();
  compute_tile((NT-1)&3);
  #undef STAGE_T

  #pragma unroll
  for (int m=0;m<MREP;m++)
    #pragma unroll
    for (int n=0;n<4;n++)
      #pragma unroll
      for (int r=0;r<4;r++){
        int row = m0 + wm*(BM/2) + m*16 + g*4 + r;
        int col = n0 + wn*64 + n*16 + ln;
        C[(size_t)row*N + col] = acc[m][n][r];
      }
}

// ---------------- RMSNorm + RoPE + layout (1 wave per (s, head-slot) row) -----
__global__ __launch_bounds__(256) void norm_rope(const float* __restrict__ QKV,
                                                 const float* __restrict__ cosb,
                                                 const float* __restrict__ sinb,
                                                 const float* __restrict__ qw,
                                                 const float* __restrict__ kw,
                                                 u16* __restrict__ Qn,
                                                 u16* __restrict__ Kn,
                                                 u16* __restrict__ Vt){
  int w = threadIdx.x>>6, lane = threadIdx.x&63;
  int row = blockIdx.x*4 + w;              // 0 .. S*48-1
  int s = row / 48, slot = row - s*48;
  const float* src = QKV + (size_t)s*NQKV + slot*HD;
  float x0 = src[lane], x1 = src[lane+64];
  if (slot < 40){
    float ss = x0*x0 + x1*x1;
    #pragma unroll
    for (int off=1; off<64; off<<=1) ss += __shfl_xor(ss, off, 64);
    float r = rsqrtf(ss*(1.0f/128.0f) + 1e-6f);
    const float* wgt = (slot < 32) ? qw : kw;
    float y0 = x0*r*wgt[lane], y1 = x1*r*wgt[lane+64];
    float c0 = cosb[(size_t)s*HD+lane], c1 = cosb[(size_t)s*HD+lane+64];
    float s0 = sinb[(size_t)s*HD+lane], s1 = sinb[(size_t)s*HD+lane+64];
    float o0 = y0*c0 - y1*s0;
    float o1 = y1*c1 + y0*s1;
    float sc = (slot < 32) ? ATT_SCALE : 1.0f;
    u16* dst = (slot < 32) ? (Qn + ((size_t)slot*S_LEN + s)*HD)
                           : (Kn + ((size_t)(slot-32)*S_LEN + s)*HD);
    dst[lane]    = (u16)f2bfbits(o0*sc);
    dst[lane+64] = (u16)f2bfbits(o1*sc);
  } else {
    int kvh = slot - 40;
    u16* dst = Vt + (size_t)kvh*HD*S_LEN + s;
    dst[(size_t)lane*S_LEN]      = (u16)f2bfbits(x0);
    dst[(size_t)(lane+64)*S_LEN] = (u16)f2bfbits(x1);
  }
}

// ---------------- flash attention v4 (causal, GQA, balanced) ----------------
__global__ __launch_bounds__(256) void flash_attn(const u16* __restrict__ Qn,
                                                  const u16* __restrict__ Kn,
                                                  const u16* __restrict__ Vt,
                                                  u16* __restrict__ O){
  __shared__ u16 Ks[2][64*128];   // [kv][d] swizzled, 16KB each
  __shared__ u16 Vs[2][128*64];   // [d][kv] swizzled, 16KB each

  const int h = blockIdx.y;
  const int w = threadIdx.x>>6, lane = threadIdx.x&63, ln = lane&15, g = lane>>4;
  const int kvh = h>>2;                        // NH/NKV = 4
  const u16* Qh = Qn + (size_t)h*S_LEN*HD;
  const u16* Kh = Kn + (size_t)kvh*S_LEN*HD;
  const u16* Vh = Vt + (size_t)kvh*HD*S_LEN;

  const int krow_w = w*4 + g;
  const int ksw    = ((krow_w)&7)<<4;
  const int kcol   = ((ln*16) ^ ksw) >> 1;
  const int vrow_w = w*8 + (lane>>3);
  const int vsw    = ((lane>>3)&7)<<4;
  const int vcol   = (((lane&7)*16) ^ vsw) >> 1;

  #define STAGE(bufi, t) { \
    int kv0_ = (t)*64; \
    _Pragma("unroll") \
    for (int p=0;p<4;p++){ \
      const u16* ga = Kh + (size_t)(kv0_ + p*16 + krow_w)*HD + kcol; \
      GLOAD16(ga, (char*)&Ks[bufi][0] + p*4096 + w*1024); \
      const u16* gv = Vh + (size_t)(p*32 + vrow_w)*S_LEN + kv0_ + vcol; \
      GLOAD16(gv, (char*)&Vs[bufi][0] + p*4096 + w*1024); \
    } \
  }

  #pragma unroll 1
  for (int ph=0; ph<2; ph++){
    const int qb = ph ? (31 - blockIdx.x) : blockIdx.x;
    const int q0 = qb*64;
    const int qrow = q0 + w*16 + ln;

    short8 qf[4];
    #pragma unroll
    for (int c=0;c<4;c++)
      qf[c] = *(const short8*)(Qh + (size_t)qrow*HD + c*32 + g*8);

    f32x4 ot[8];
    #pragma unroll
    for (int dt=0;dt<8;dt++) ot[dt] = (f32x4){0.f,0.f,0.f,0.f};
    float m_run = -1e30f, l_run = 0.f;

    const int nt = qb + 1;

    STAGE(0, 0);
    __syncthreads();

    for (int t=0; t<nt; ++t){
      const int cur = t&1;
      if (t+1 < nt) STAGE(cur^1, t+1);
      const int kv0 = t*64;

      // QK^T: S^T[kv][q] tiles, A = K from LDS, B = qf
      f32x4 st[4];
      #pragma unroll
      for (int mt=0; mt<4; mt++){
        f32x4 acc = (f32x4){0.f,0.f,0.f,0.f};
        #pragma unroll
        for (int c=0;c<4;c++){
          short8 kf = *(const short8*)((const char*)&Ks[cur][0]
                        + (mt*16+ln)*256 + ((c*64 + g*16) ^ ((ln&7)<<4)));
          acc = __builtin_amdgcn_mfma_f32_16x16x32_bf16(kf, qf[c], acc, 0,0,0);
        }
        st[mt] = acc;
      }

      // softmax (per-lane row stats, q = ln); only diagonal tile needs mask
      float p[4][4];
      float mtile = -1e30f;
      if (t < qb){
        #pragma unroll
        for (int mt=0; mt<4; mt++)
          #pragma unroll
          for (int r=0;r<4;r++){
            p[mt][r] = st[mt][r];
            mtile = fmaxf(mtile, st[mt][r]);
          }
      } else {
        #pragma unroll
        for (int mt=0; mt<4; mt++)
          #pragma unroll
          for (int r=0;r<4;r++){
            int kv = kv0 + mt*16 + 4*g + r;
            float sv = (kv <= qrow) ? st[mt][r] : -1e30f;
            p[mt][r] = sv;
            mtile = fmaxf(mtile, sv);
          }
      }
      mtile = fmaxf(mtile, __shfl_xor(mtile, 16, 64));
      mtile = fmaxf(mtile, __shfl_xor(mtile, 32, 64));

      bool defer = __all(mtile <= m_run + 8.0f);
      float m_new = defer ? m_run : fmaxf(m_run, mtile);

      float l_tile = 0.f;
      #pragma unroll
      for (int mt=0; mt<4; mt++)
        #pragma unroll
        for (int r=0;r<4;r++){
          float e = exp2f((p[mt][r] - m_new)*LOG2E);
          p[mt][r] = e;
          l_tile += e;
        }
      l_tile += __shfl_xor(l_tile, 16, 64);
      l_tile += __shfl_xor(l_tile, 32, 64);
      if (defer){
        l_run += l_tile;
      } else {
        float alpha = exp2f((m_run - m_new)*LOG2E);
        l_run = l_run*alpha + l_tile;
        m_run = m_new;
        #pragma unroll
        for (int dt=0;dt<8;dt++) ot[dt] *= alpha;
      }

      // P redistribution per 32-kv half (cvt_pk packing, shfl recipe)
      short8 pf[2];
      #pragma unroll
      for (int ks2=0; ks2<2; ks2++){
        unsigned pk00 = cvtpk(p[2*ks2  ][0], p[2*ks2  ][1]);
        unsigned pk01 = cvtpk(p[2*ks2  ][2], p[2*ks2  ][3]);
        unsigned pk10 = cvtpk(p[2*ks2+1][0], p[2*ks2+1][1]);
        unsigned pk11 = cvtpk(p[2*ks2+1][2], p[2*ks2+1][3]);
        int src0 = (((2*g  )&3)<<4) | ln;
        int src1 = (((2*g+1)&3)<<4) | ln;
        unsigned t00 = (unsigned)__shfl((int)pk00, src0, 64);
        unsigned t10 = (unsigned)__shfl((int)pk10, src0, 64);
        unsigned t01 = (unsigned)__shfl((int)pk01, src0, 64);
        unsigned t11 = (unsigned)__shfl((int)pk11, src0, 64);
        unsigned u00 = (unsigned)__shfl((int)pk00, src1, 64);
        unsigned u10 = (unsigned)__shfl((int)pk10, src1, 64);
        unsigned u01 = (unsigned)__shfl((int)pk01, src1, 64);
        unsigned u11 = (unsigned)__shfl((int)pk11, src1, 64);
        bool hiv = (g >= 2);
        union { unsigned u[4]; short8 s; } pw;
        pw.u[0] = hiv ? t10 : t00;
        pw.u[1] = hiv ? t11 : t01;
        pw.u[2] = hiv ? u10 : u00;
        pw.u[3] = hiv ? u11 : u01;
        pf[ks2] = pw.s;
      }

      // PV: O^T[d][q] += V^T chunks * P^T, A = V from LDS
      #pragma unroll
      for (int dt=0;dt<8;dt++){
        #pragma unroll
        for (int ks2=0; ks2<2; ks2++){
          short8 vf = *(const short8*)((const char*)&Vs[cur][0]
                        + (dt*16+ln)*128 + ((ks2*64 + g*16) ^ ((ln&7)<<4)));
          ot[dt] = __builtin_amdgcn_mfma_f32_16x16x32_bf16(vf, pf[ks2], ot[dt], 0,0,0);
        }
      }
      __syncthreads();
    }

    float inv = 1.0f / l_run;
    u16* orow = O + (size_t)qrow*(NH*HD) + h*HD;
    #pragma unroll
    for (int dt=0;dt<8;dt++){
      #pragma unroll
      for (int rr=0; rr<4; rr+=2){
        unsigned pkd = cvtpk(ot[dt][rr]*inv, ot[dt][rr+1]*inv);
        *(unsigned*)(orow + dt*16 + g*4 + rr) = pkd;
      }
    }
  }
  #undef STAGE
}

// ---------------- host ----------------
extern "C" void kernel_launch(void* const* d_in, const int* in_sizes, int n_in,
                              void* d_out, int out_size, void* d_ws, size_t ws_size,
                              hipStream_t stream){
  (void)in_sizes; (void)n_in; (void)out_size; (void)ws_size;
  const float* hs   = (const float*)d_in[0];
  const float* cosb = (const float*)d_in[1];
  const float* sinb = (const float*)d_in[2];
  const float* Wq   = (const float*)d_in[3];
  const float* Wk   = (const float*)d_in[4];
  const float* Wv   = (const float*)d_in[5];
  const float* Wo   = (const float*)d_in[6];
  const float* qw   = (const float*)d_in[7];
  const float* kw   = (const float*)d_in[8];
  float* out = (float*)d_out;

  char* ws = (char*)d_ws;
  u16*   Xb    = (u16*)  (ws);
  u16*   WQKV  = (u16*)  (ws + 16777216);
  float* QKV   = (float*)(ws + 67108864);
  u16*   attnB = (u16*)  (ws + 67108864);   // overlay: QKV dead after norm_rope
  u16*   Qn    = (u16*)  (ws + 117440512);
  u16*   Kn    = (u16*)  (ws + 134217728);
  u16*   Vt    = (u16*)  (ws + 138412032);
  u16*   Wob   = WQKV;                      // overlay: WQKV dead after GEMM1

  cvt_bf16<<<(S_LEN*HIDD/8)/256, 256, 0, stream>>>(hs, Xb, S_LEN*HIDD/8);
  cvt_bf16<<<(NH*HD*HIDD/8)/256, 256, 0, stream>>>(Wq, WQKV, NH*HD*HIDD/8);
  cvt_bf16<<<(NKV*HD*HIDD/8)/256, 256, 0, stream>>>(Wk, WQKV + (size_t)NH*HD*HIDD, NKV*HD*HIDD/8);
  cvt_bf16<<<(NKV*HD*HIDD/8)/256, 256, 0, stream>>>(Wv, WQKV + (size_t)(NH+NKV)*HD*HIDD, NKV*HD*HIDD/8);
  // GEMM1: [2048 x 4096] x [6144 x 4096]^T
  gemm_bt_big<256><<<192, 512, 0, stream>>>(Xb, WQKV, QKV, NQKV, HIDD, NQKV/256);
  norm_rope<<<(S_LEN*48)/4, 256, 0, stream>>>(QKV, cosb, sinb, qw, kw, Qn, Kn, Vt);
  cvt_bf16<<<(HIDD*NH*HD/8)/256, 256, 0, stream>>>(Wo, Wob, HIDD*NH*HD/8);
  // flash attention: 16 complementary pairs x 32 heads = 512 blocks
  flash_attn<<<dim3(16, NH), 256, 0, stream>>>(Qn, Kn, Vt, attnB);
  // GEMM2: [2048 x 4096] x [4096 x 4096]^T
  gemm_bt_big<128><<<256, 512, 0, stream>>>(attnB, Wob, out, HIDD, HIDD, HIDD/256);
}

// Round 7
// 342.245 us; speedup vs baseline: 1.7790x; 1.2370x over previous
//
#include <hip/hip_runtime.h>
#include <hip/hip_bf16.h>
#include <stdint.h>

#define S_LEN 2048
#define HIDD  4096
#define NH    32
#define NKV   8
#define HD    128
#define NQKV  6144   // (NH + 2*NKV) * HD
#define ATT_SCALE 0.08838834764831845f
#define LOG2E 1.4426950408889634f

typedef unsigned short u16;
typedef __attribute__((ext_vector_type(8))) short short8;
typedef __attribute__((ext_vector_type(4))) float f32x4;

__device__ __forceinline__ unsigned f2bfbits(float f){
  union{float f; unsigned u;} v; v.f = f;
  return (v.u + 0x7FFFu + ((v.u>>16)&1u)) >> 16;
}
__device__ __forceinline__ unsigned packbf(float a, float b){
  return f2bfbits(a) | (f2bfbits(b)<<16);
}
__device__ __forceinline__ unsigned cvtpk(float lo, float hi){
  unsigned r;
  asm("v_cvt_pk_bf16_f32 %0, %1, %2" : "=v"(r) : "v"(lo), "v"(hi));
  return r;
}

#define GLOAD16(g, l) __builtin_amdgcn_global_load_lds( \
    (__attribute__((address_space(1))) void*)(g), \
    (__attribute__((address_space(3))) void*)(l), 16, 0, 0)

#define VMWAIT(n) asm volatile("s_waitcnt vmcnt(" #n ")" ::: "memory")

// ---------------- fp32 -> bf16 convert (8 elems/thread) ----------------
__global__ __launch_bounds__(256) void cvt_bf16(const float* __restrict__ in,
                                                u16* __restrict__ out, int n8){
  int i = blockIdx.x*256 + threadIdx.x;
  if (i >= n8) return;
  const float4* p = (const float4*)in;
  float4 a = p[2*i], b = p[2*i+1];
  union { unsigned u[4]; short8 s; } o;
  o.u[0] = packbf(a.x, a.y); o.u[1] = packbf(a.z, a.w);
  o.u[2] = packbf(b.x, b.y); o.u[3] = packbf(b.z, b.w);
  *(short8*)(out + (size_t)i*8) = o.s;
}

// ============ 8-phase pipelined bf16 GEMM, C = A * B^T (fp32 C) =============
// BM x BN tile, BK=64 (2 K-tiles per iteration, 8 phases), 8 waves (2M x 4N).
// LDS: per buffer (tile parity) A/B split into k-half regions; phase p stages
// the region consumed at phase p-1/p-2 (ledger in session notes). Uniform
// vmcnt(2*LP) at even phases keeps 2 stage-points in flight; never drains.
// B staged padded to 256 rows (BN=192 pads land in workspace, never read).
template<int BM, int BN>
__global__ __launch_bounds__(512) void gemm_8ph(const u16* __restrict__ A,
                                                const u16* __restrict__ B,
                                                float* __restrict__ C,
                                                int N, int K, int nbx){
  constexpr int MREP = BM/32;     // m-frags per wave (8 | 4)
  constexpr int MH   = MREP/2;    // m-frags per phase
  constexpr int NF   = BN/64;     // n-frags per wave (3 | 4)
  constexpr int AH   = BM/128;    // 16KB row-halves per A k-half region (2 | 1)
  constexpr int ASZ  = BM*64;     // bytes per (buf,khalf) A region
  __shared__ __align__(16) char lds[4*ASZ + 65536];

  const int tid = threadIdx.x;
  const int w = tid>>6, lane = tid&63, ln = lane&15, g = lane>>4;
  const int wm = w>>2, wn = w&3;
  const int swz5 = ((ln>>3)&1)<<5;

  const int nwg = gridDim.x, flat = blockIdx.x;
  const int wg = (flat&7)*(nwg>>3) + (flat>>3);
  const int by = wg/nbx, bx = wg - by*nbx;
  const int m0 = by*BM, n0 = bx*BN;

  const int rs   = ((tid>>6)<<4) + ((tid&63)>>2);
  const int ksrc = ((tid&3)<<3) ^ (((tid>>5)&1)<<4);
  const u16* srcA[AH];
  #pragma unroll
  for (int h=0;h<AH;h++) srcA[h] = A + (size_t)(m0 + h*128 + rs)*K + ksrc;
  const u16* srcB[2];
  #pragma unroll
  for (int h=0;h<2;h++)  srcB[h] = B + (size_t)(n0 + h*128 + rs)*K + ksrc;

  #define AREG(bf,kh) (lds + ((bf)*2 + (kh))*ASZ)
  #define BREG(bf,kh) (lds + 4*ASZ + ((bf)*2 + (kh))*16384)

  #define STAGEPT(t, kh, bf) { const int off_ = (t)*64 + (kh)*32;                 \
    _Pragma("unroll") for (int h=0;h<AH;h++)                                      \
      GLOAD16(srcA[h]+off_, AREG(bf,kh) + h*8192 + w*1024);                       \
    _Pragma("unroll") for (int h=0;h<2;h++)                                       \
      GLOAD16(srcB[h]+off_, BREG(bf,kh) + h*8192 + w*1024); }

  f32x4 acc[MREP][NF];
  #pragma unroll
  for (int m=0;m<MREP;m++)
    #pragma unroll
    for (int n=0;n<NF;n++) acc[m][n] = (f32x4){0.f,0.f,0.f,0.f};
  short8 a_[MH], b_[NF];

  #define READA(bf,kh,mh) { _Pragma("unroll") for (int m=0;m<MH;m++)              \
    a_[m] = *(const short8*)(AREG(bf,kh) + (wm*MREP+(mh)*MH+m)*1024 + ln*64 + ((g*16)^swz5)); }
  #define READB(bf,kh) { _Pragma("unroll") for (int n=0;n<NF;n++)                 \
    b_[n] = *(const short8*)(BREG(bf,kh) + (wn*NF+n)*1024 + ln*64 + ((g*16)^swz5)); }
  #define MFMACLU(mh) { __builtin_amdgcn_s_setprio(1);                            \
    _Pragma("unroll") for (int m=0;m<MH;m++)                                      \
      _Pragma("unroll") for (int n=0;n<NF;n++)                                    \
        acc[(mh)*MH+m][n] = __builtin_amdgcn_mfma_f32_16x16x32_bf16(a_[m], b_[n], acc[(mh)*MH+m][n], 0,0,0); \
    __builtin_amdgcn_s_setprio(0); }
  #define BARR() __builtin_amdgcn_s_barrier()
  #define LGK0() do{ asm volatile("s_waitcnt lgkmcnt(0)" ::: "memory");           \
                     __builtin_amdgcn_sched_barrier(0); }while(0)
  #define VMSTEADY() do{ if constexpr (AH==2) { VMWAIT(8); } else { VMWAIT(6); } }while(0)
  #define VMHALF()   do{ if constexpr (AH==2) { VMWAIT(4); } else { VMWAIT(3); } }while(0)

  // prologue: tile0 (buf0) fully, tile1 (buf1) k0
  STAGEPT(0,0,0); STAGEPT(0,1,0); STAGEPT(1,0,1);
  VMWAIT(0); BARR();

  const int NIT = (K>>6)/2;   // K/64 tiles, 2 per iteration
  #pragma unroll 1
  for (int it=0; it<NIT; ++it){
    const bool last = (it == NIT-1);
    const int t0 = 2*it;
    // P1: compute buf0 k0 mh0 ; stage tile t0+1 k1 -> buf1.k1 (consumed prev P7/P8)
    READA(0,0,0); READB(0,0); STAGEPT(t0+1, 1, 1);
    BARR(); LGK0(); MFMACLU(0); BARR();
    // P2
    READA(0,0,1);
    BARR(); LGK0(); MFMACLU(1); VMSTEADY(); BARR();
    // P3: stage tile t0+2 k0 -> buf0.k0 (consumed P1/P2)
    READA(0,1,0); READB(0,1); if (!last) STAGEPT(t0+2, 0, 0);
    BARR(); LGK0(); MFMACLU(0); BARR();
    // P4
    READA(0,1,1);
    BARR(); LGK0(); MFMACLU(1); if (last) { VMHALF(); } else { VMSTEADY(); } BARR();
    // P5: stage tile t0+2 k1 -> buf0.k1 (consumed P3/P4)
    READA(1,0,0); READB(1,0); if (!last) STAGEPT(t0+2, 1, 0);
    BARR(); LGK0(); MFMACLU(0); BARR();
    // P6
    READA(1,0,1);
    BARR(); LGK0(); MFMACLU(1); if (last) { VMWAIT(0); } else { VMSTEADY(); } BARR();
    // P7: stage tile t0+3 k0 -> buf1.k0 (consumed P5/P6)
    READA(1,1,0); READB(1,1); if (!last) STAGEPT(t0+3, 0, 1);
    BARR(); LGK0(); MFMACLU(0); BARR();
    // P8
    READA(1,1,1);
    BARR(); LGK0(); MFMACLU(1); if (!last) { VMSTEADY(); } BARR();
  }

  #pragma unroll
  for (int mi=0; mi<MREP; mi++)
    #pragma unroll
    for (int n=0; n<NF; n++)
      #pragma unroll
      for (int r=0;r<4;r++){
        int row = m0 + (wm*MREP+mi)*16 + g*4 + r;
        int col = n0 + wn*(NF*16) + n*16 + ln;
        C[(size_t)row*N + col] = acc[mi][n][r];
      }
  #undef AREG
  #undef BREG
  #undef STAGEPT
  #undef READA
  #undef READB
  #undef MFMACLU
  #undef BARR
  #undef LGK0
  #undef VMSTEADY
  #undef VMHALF
}

// ---------------- RMSNorm + RoPE + layout (1 wave per (s, head-slot) row) -----
__global__ __launch_bounds__(256) void norm_rope(const float* __restrict__ QKV,
                                                 const float* __restrict__ cosb,
                                                 const float* __restrict__ sinb,
                                                 const float* __restrict__ qw,
                                                 const float* __restrict__ kw,
                                                 u16* __restrict__ Qn,
                                                 u16* __restrict__ Kn,
                                                 u16* __restrict__ Vt){
  int w = threadIdx.x>>6, lane = threadIdx.x&63;
  int row = blockIdx.x*4 + w;              // 0 .. S*48-1
  int s = row / 48, slot = row - s*48;
  const float* src = QKV + (size_t)s*NQKV + slot*HD;
  float x0 = src[lane], x1 = src[lane+64];
  if (slot < 40){
    float ss = x0*x0 + x1*x1;
    #pragma unroll
    for (int off=1; off<64; off<<=1) ss += __shfl_xor(ss, off, 64);
    float r = rsqrtf(ss*(1.0f/128.0f) + 1e-6f);
    const float* wgt = (slot < 32) ? qw : kw;
    float y0 = x0*r*wgt[lane], y1 = x1*r*wgt[lane+64];
    float c0 = cosb[(size_t)s*HD+lane], c1 = cosb[(size_t)s*HD+lane+64];
    float s0 = sinb[(size_t)s*HD+lane], s1 = sinb[(size_t)s*HD+lane+64];
    float o0 = y0*c0 - y1*s0;
    float o1 = y1*c1 + y0*s1;
    float sc = (slot < 32) ? ATT_SCALE : 1.0f;
    u16* dst = (slot < 32) ? (Qn + ((size_t)slot*S_LEN + s)*HD)
                           : (Kn + ((size_t)(slot-32)*S_LEN + s)*HD);
    dst[lane]    = (u16)f2bfbits(o0*sc);
    dst[lane+64] = (u16)f2bfbits(o1*sc);
  } else {
    int kvh = slot - 40;
    u16* dst = Vt + (size_t)kvh*HD*S_LEN + s;
    dst[(size_t)lane*S_LEN]      = (u16)f2bfbits(x0);
    dst[(size_t)(lane+64)*S_LEN] = (u16)f2bfbits(x1);
  }
}

// ---------------- flash attention v4 (causal, GQA, balanced) ----------------
__global__ __launch_bounds__(256) void flash_attn(const u16* __restrict__ Qn,
                                                  const u16* __restrict__ Kn,
                                                  const u16* __restrict__ Vt,
                                                  u16* __restrict__ O){
  __shared__ u16 Ks[2][64*128];   // [kv][d] swizzled, 16KB each
  __shared__ u16 Vs[2][128*64];   // [d][kv] swizzled, 16KB each

  const int h = blockIdx.y;
  const int w = threadIdx.x>>6, lane = threadIdx.x&63, ln = lane&15, g = lane>>4;
  const int kvh = h>>2;                        // NH/NKV = 4
  const u16* Qh = Qn + (size_t)h*S_LEN*HD;
  const u16* Kh = Kn + (size_t)kvh*S_LEN*HD;
  const u16* Vh = Vt + (size_t)kvh*HD*S_LEN;

  const int krow_w = w*4 + g;
  const int ksw    = ((krow_w)&7)<<4;
  const int kcol   = ((ln*16) ^ ksw) >> 1;
  const int vrow_w = w*8 + (lane>>3);
  const int vsw    = ((lane>>3)&7)<<4;
  const int vcol   = (((lane&7)*16) ^ vsw) >> 1;

  #define STAGE(bufi, t) { \
    int kv0_ = (t)*64; \
    _Pragma("unroll") \
    for (int p=0;p<4;p++){ \
      const u16* ga = Kh + (size_t)(kv0_ + p*16 + krow_w)*HD + kcol; \
      GLOAD16(ga, (char*)&Ks[bufi][0] + p*4096 + w*1024); \
      const u16* gv = Vh + (size_t)(p*32 + vrow_w)*S_LEN + kv0_ + vcol; \
      GLOAD16(gv, (char*)&Vs[bufi][0] + p*4096 + w*1024); \
    } \
  }

  #pragma unroll 1
  for (int ph=0; ph<2; ph++){
    const int qb = ph ? (31 - blockIdx.x) : blockIdx.x;
    const int q0 = qb*64;
    const int qrow = q0 + w*16 + ln;

    short8 qf[4];
    #pragma unroll
    for (int c=0;c<4;c++)
      qf[c] = *(const short8*)(Qh + (size_t)qrow*HD + c*32 + g*8);

    f32x4 ot[8];
    #pragma unroll
    for (int dt=0;dt<8;dt++) ot[dt] = (f32x4){0.f,0.f,0.f,0.f};
    float m_run = -1e30f, l_run = 0.f;

    const int nt = qb + 1;

    STAGE(0, 0);
    __syncthreads();

    for (int t=0; t<nt; ++t){
      const int cur = t&1;
      if (t+1 < nt) STAGE(cur^1, t+1);
      const int kv0 = t*64;

      f32x4 st[4];
      #pragma unroll
      for (int mt=0; mt<4; mt++){
        f32x4 acc = (f32x4){0.f,0.f,0.f,0.f};
        #pragma unroll
        for (int c=0;c<4;c++){
          short8 kf = *(const short8*)((const char*)&Ks[cur][0]
                        + (mt*16+ln)*256 + ((c*64 + g*16) ^ ((ln&7)<<4)));
          acc = __builtin_amdgcn_mfma_f32_16x16x32_bf16(kf, qf[c], acc, 0,0,0);
        }
        st[mt] = acc;
      }

      float p[4][4];
      float mtile = -1e30f;
      if (t < qb){
        #pragma unroll
        for (int mt=0; mt<4; mt++)
          #pragma unroll
          for (int r=0;r<4;r++){
            p[mt][r] = st[mt][r];
            mtile = fmaxf(mtile, st[mt][r]);
          }
      } else {
        #pragma unroll
        for (int mt=0; mt<4; mt++)
          #pragma unroll
          for (int r=0;r<4;r++){
            int kv = kv0 + mt*16 + 4*g + r;
            float sv = (kv <= qrow) ? st[mt][r] : -1e30f;
            p[mt][r] = sv;
            mtile = fmaxf(mtile, sv);
          }
      }
      mtile = fmaxf(mtile, __shfl_xor(mtile, 16, 64));
      mtile = fmaxf(mtile, __shfl_xor(mtile, 32, 64));

      bool defer = __all(mtile <= m_run + 8.0f);
      float m_new = defer ? m_run : fmaxf(m_run, mtile);

      float l_tile = 0.f;
      #pragma unroll
      for (int mt=0; mt<4; mt++)
        #pragma unroll
        for (int r=0;r<4;r++){
          float e = exp2f((p[mt][r] - m_new)*LOG2E);
          p[mt][r] = e;
          l_tile += e;
        }
      l_tile += __shfl_xor(l_tile, 16, 64);
      l_tile += __shfl_xor(l_tile, 32, 64);
      if (defer){
        l_run += l_tile;
      } else {
        float alpha = exp2f((m_run - m_new)*LOG2E);
        l_run = l_run*alpha + l_tile;
        m_run = m_new;
        #pragma unroll
        for (int dt=0;dt<8;dt++) ot[dt] *= alpha;
      }

      short8 pf[2];
      #pragma unroll
      for (int ks2=0; ks2<2; ks2++){
        unsigned pk00 = cvtpk(p[2*ks2  ][0], p[2*ks2  ][1]);
        unsigned pk01 = cvtpk(p[2*ks2  ][2], p[2*ks2  ][3]);
        unsigned pk10 = cvtpk(p[2*ks2+1][0], p[2*ks2+1][1]);
        unsigned pk11 = cvtpk(p[2*ks2+1][2], p[2*ks2+1][3]);
        int src0 = (((2*g  )&3)<<4) | ln;
        int src1 = (((2*g+1)&3)<<4) | ln;
        unsigned t00 = (unsigned)__shfl((int)pk00, src0, 64);
        unsigned t10 = (unsigned)__shfl((int)pk10, src0, 64);
        unsigned t01 = (unsigned)__shfl((int)pk01, src0, 64);
        unsigned t11 = (unsigned)__shfl((int)pk11, src0, 64);
        unsigned u00 = (unsigned)__shfl((int)pk00, src1, 64);
        unsigned u10 = (unsigned)__shfl((int)pk10, src1, 64);
        unsigned u01 = (unsigned)__shfl((int)pk01, src1, 64);
        unsigned u11 = (unsigned)__shfl((int)pk11, src1, 64);
        bool hiv = (g >= 2);
        union { unsigned u[4]; short8 s; } pw;
        pw.u[0] = hiv ? t10 : t00;
        pw.u[1] = hiv ? t11 : t01;
        pw.u[2] = hiv ? u10 : u00;
        pw.u[3] = hiv ? u11 : u01;
        pf[ks2] = pw.s;
      }

      #pragma unroll
      for (int dt=0;dt<8;dt++){
        #pragma unroll
        for (int ks2=0; ks2<2; ks2++){
          short8 vf = *(const short8*)((const char*)&Vs[cur][0]
                        + (dt*16+ln)*128 + ((ks2*64 + g*16) ^ ((ln&7)<<4)));
          ot[dt] = __builtin_amdgcn_mfma_f32_16x16x32_bf16(vf, pf[ks2], ot[dt], 0,0,0);
        }
      }
      __syncthreads();
    }

    float inv = 1.0f / l_run;
    u16* orow = O + (size_t)qrow*(NH*HD) + h*HD;
    #pragma unroll
    for (int dt=0;dt<8;dt++){
      #pragma unroll
      for (int rr=0; rr<4; rr+=2){
        unsigned pkd = cvtpk(ot[dt][rr]*inv, ot[dt][rr+1]*inv);
        *(unsigned*)(orow + dt*16 + g*4 + rr) = pkd;
      }
    }
  }
  #undef STAGE
}

// ---------------- host ----------------
extern "C" void kernel_launch(void* const* d_in, const int* in_sizes, int n_in,
                              void* d_out, int out_size, void* d_ws, size_t ws_size,
                              hipStream_t stream){
  (void)in_sizes; (void)n_in; (void)out_size; (void)ws_size;
  const float* hs   = (const float*)d_in[0];
  const float* cosb = (const float*)d_in[1];
  const float* sinb = (const float*)d_in[2];
  const float* Wq   = (const float*)d_in[3];
  const float* Wk   = (const float*)d_in[4];
  const float* Wv   = (const float*)d_in[5];
  const float* Wo   = (const float*)d_in[6];
  const float* qw   = (const float*)d_in[7];
  const float* kw   = (const float*)d_in[8];
  float* out = (float*)d_out;

  char* ws = (char*)d_ws;
  u16*   Xb    = (u16*)  (ws);
  u16*   WQKV  = (u16*)  (ws + 16777216);
  float* QKV   = (float*)(ws + 67108864);
  u16*   attnB = (u16*)  (ws + 67108864);   // overlay: QKV dead after norm_rope
  u16*   Qn    = (u16*)  (ws + 117440512);
  u16*   Kn    = (u16*)  (ws + 134217728);
  u16*   Vt    = (u16*)  (ws + 138412032);
  u16*   Wob   = WQKV;                      // overlay: WQKV dead after GEMM1

  cvt_bf16<<<(S_LEN*HIDD/8)/256, 256, 0, stream>>>(hs, Xb, S_LEN*HIDD/8);
  cvt_bf16<<<(NH*HD*HIDD/8)/256, 256, 0, stream>>>(Wq, WQKV, NH*HD*HIDD/8);
  cvt_bf16<<<(NKV*HD*HIDD/8)/256, 256, 0, stream>>>(Wk, WQKV + (size_t)NH*HD*HIDD, NKV*HD*HIDD/8);
  cvt_bf16<<<(NKV*HD*HIDD/8)/256, 256, 0, stream>>>(Wv, WQKV + (size_t)(NH+NKV)*HD*HIDD, NKV*HD*HIDD/8);
  // GEMM1: [2048 x 4096] x [6144 x 4096]^T, 256x192 tiles -> 8x32 = 256 blocks
  gemm_8ph<256,192><<<256, 512, 0, stream>>>(Xb, WQKV, QKV, NQKV, HIDD, NQKV/192);
  norm_rope<<<(S_LEN*48)/4, 256, 0, stream>>>(QKV, cosb, sinb, qw, kw, Qn, Kn, Vt);
  cvt_bf16<<<(HIDD*NH*HD/8)/256, 256, 0, stream>>>(Wo, Wob, HIDD*NH*HD/8);
  // flash attention: 16 complementary pairs x 32 heads = 512 blocks
  flash_attn<<<dim3(16, NH), 256, 0, stream>>>(Qn, Kn, Vt, attnB);
  // GEMM2: [2048 x 4096] x [4096 x 4096]^T, 128x256 tiles -> 16x16 = 256 blocks
  gemm_8ph<128,256><<<256, 512, 0, stream>>>(attnB, Wob, out, HIDD, HIDD, HIDD/256);
}

// Round 8
// 342.124 us; speedup vs baseline: 1.7796x; 1.0004x over previous
//
#include <hip/hip_runtime.h>
#include <hip/hip_bf16.h>
#include <stdint.h>

#define S_LEN 2048
#define HIDD  4096
#define NH    32
#define NKV   8
#define HD    128
#define NQKV  6144   // (NH + 2*NKV) * HD
#define ATT_SCALE 0.08838834764831845f
#define LOG2E 1.4426950408889634f

typedef unsigned short u16;
typedef __attribute__((ext_vector_type(8))) short short8;
typedef __attribute__((ext_vector_type(4))) float f32x4;

__device__ __forceinline__ unsigned f2bfbits(float f){
  union{float f; unsigned u;} v; v.f = f;
  return (v.u + 0x7FFFu + ((v.u>>16)&1u)) >> 16;
}
__device__ __forceinline__ unsigned packbf(float a, float b){
  return f2bfbits(a) | (f2bfbits(b)<<16);
}
__device__ __forceinline__ unsigned cvtpk(float lo, float hi){
  unsigned r;
  asm("v_cvt_pk_bf16_f32 %0, %1, %2" : "=v"(r) : "v"(lo), "v"(hi));
  return r;
}

#define GLOAD16(g, l) __builtin_amdgcn_global_load_lds( \
    (__attribute__((address_space(1))) void*)(g), \
    (__attribute__((address_space(3))) void*)(l), 16, 0, 0)

#define VMWAIT(n) asm volatile("s_waitcnt vmcnt(" #n ")" ::: "memory")

// ---------------- fp32 -> bf16 convert (8 elems/thread) ----------------
__global__ __launch_bounds__(256) void cvt_bf16(const float* __restrict__ in,
                                                u16* __restrict__ out, int n8){
  int i = blockIdx.x*256 + threadIdx.x;
  if (i >= n8) return;
  const float4* p = (const float4*)in;
  float4 a = p[2*i], b = p[2*i+1];
  union { unsigned u[4]; short8 s; } o;
  o.u[0] = packbf(a.x, a.y); o.u[1] = packbf(a.z, a.w);
  o.u[2] = packbf(b.x, b.y); o.u[3] = packbf(b.z, b.w);
  *(short8*)(out + (size_t)i*8) = o.s;
}

// ============ 4-phase pipelined bf16 GEMM, C = A * B^T (fp32 C) =============
// BM x BN tile, 2 K64-tiles per iteration, 4 phases (full-M x one k-half per
// phase): GEMM1 24 MFMA/phase, GEMM2 16 MFMA/phase. 8 waves (2M x 4N).
// One stage-point (LP loads) per phase; uniform vmcnt(2*LP) at phase end
// retires the SP staged 2 phases ago = exactly the region read next phase.
// Stage-write safety: region R staged only after the closing barrier of R's
// consuming phase (all waves' lgkmcnt(0) precede that barrier).
// B staged padded to 256 rows (BN=192 pads land in workspace, never read).
template<int BM, int BN>
__global__ __launch_bounds__(512) void gemm_4ph(const u16* __restrict__ A,
                                                const u16* __restrict__ B,
                                                float* __restrict__ C,
                                                int N, int K, int nbx){
  constexpr int MREP = BM/32;     // m-frags per wave (8 | 4)
  constexpr int NF   = BN/64;     // n-frags per wave (3 | 4)
  constexpr int AH   = BM/128;    // 16KB halves per A k-half region (2 | 1)
  constexpr int ASZ  = BM*64;     // bytes per (buf,khalf) A region
  __shared__ __align__(16) char lds[4*ASZ + 65536];

  const int tid = threadIdx.x;
  const int w = tid>>6, lane = tid&63, ln = lane&15, g = lane>>4;
  const int wm = w>>2, wn = w&3;
  const int swz5 = ((ln>>3)&1)<<5;

  const int nwg = gridDim.x, flat = blockIdx.x;
  const int wg = (flat&7)*(nwg>>3) + (flat>>3);
  const int by = wg/nbx, bx = wg - by*nbx;
  const int m0 = by*BM, n0 = bx*BN;

  const int rs   = ((tid>>6)<<4) + ((tid&63)>>2);
  const int ksrc = ((tid&3)<<3) ^ (((tid>>5)&1)<<4);
  const u16* srcA[AH];
  #pragma unroll
  for (int h=0;h<AH;h++) srcA[h] = A + (size_t)(m0 + h*128 + rs)*K + ksrc;
  const u16* srcB[2];
  #pragma unroll
  for (int h=0;h<2;h++)  srcB[h] = B + (size_t)(n0 + h*128 + rs)*K + ksrc;

  #define AREG(bf,kh) (lds + ((bf)*2 + (kh))*ASZ)
  #define BREG(bf,kh) (lds + 4*ASZ + ((bf)*2 + (kh))*16384)

  #define STAGEPT(t, kh, bf) { const int off_ = (t)*64 + (kh)*32;                 \
    _Pragma("unroll") for (int h=0;h<AH;h++)                                      \
      GLOAD16(srcA[h]+off_, AREG(bf,kh) + h*8192 + w*1024);                       \
    _Pragma("unroll") for (int h=0;h<2;h++)                                       \
      GLOAD16(srcB[h]+off_, BREG(bf,kh) + h*8192 + w*1024); }

  f32x4 acc[MREP][NF];
  #pragma unroll
  for (int m=0;m<MREP;m++)
    #pragma unroll
    for (int n=0;n<NF;n++) acc[m][n] = (f32x4){0.f,0.f,0.f,0.f};
  short8 a_[MREP], b_[NF];

  #define READA(bf,kh) { _Pragma("unroll") for (int m=0;m<MREP;m++)               \
    a_[m] = *(const short8*)(AREG(bf,kh) + (wm*MREP+m)*1024 + ln*64 + ((g*16)^swz5)); }
  #define READB(bf,kh) { _Pragma("unroll") for (int n=0;n<NF;n++)                 \
    b_[n] = *(const short8*)(BREG(bf,kh) + (wn*NF+n)*1024 + ln*64 + ((g*16)^swz5)); }
  #define MFMACLU() { __builtin_amdgcn_s_setprio(1);                              \
    _Pragma("unroll") for (int m=0;m<MREP;m++)                                    \
      _Pragma("unroll") for (int n=0;n<NF;n++)                                    \
        acc[m][n] = __builtin_amdgcn_mfma_f32_16x16x32_bf16(a_[m], b_[n], acc[m][n], 0,0,0); \
    __builtin_amdgcn_s_setprio(0); }
  #define BARR() __builtin_amdgcn_s_barrier()
  #define LGK0() do{ asm volatile("s_waitcnt lgkmcnt(0)" ::: "memory");           \
                     __builtin_amdgcn_sched_barrier(0); }while(0)
  #define VM2LP() do{ if constexpr (AH==2) { VMWAIT(8); } else { VMWAIT(6); } }while(0)
  #define VM1LP() do{ if constexpr (AH==2) { VMWAIT(4); } else { VMWAIT(3); } }while(0)

  // prologue: tile0 both halves, tile1 k0
  STAGEPT(0,0,0); STAGEPT(0,1,0); STAGEPT(1,0,1);
  VMWAIT(0); BARR();

  const int NIT = K>>7;   // 2 K64-tiles per iteration
  #pragma unroll 1
  for (int it=0; it<NIT; ++it){
    const bool last = (it == NIT-1);
    const int t0 = 2*it;
    // P1: tile t0 k0 ; stage (t0+1,k1)->buf1.k1 (consumed prev-iter P4)
    READA(0,0); READB(0,0); STAGEPT(t0+1, 1, 1);
    BARR(); LGK0(); MFMACLU(); VM2LP(); BARR();
    // P2: tile t0 k1 ; stage (t0+2,k0)->buf0.k0 (consumed P1)
    READA(0,1); READB(0,1); if (!last) STAGEPT(t0+2, 0, 0);
    BARR(); LGK0(); MFMACLU(); if (last) { VM1LP(); } else { VM2LP(); } BARR();
    // P3: tile t0+1 k0 ; stage (t0+2,k1)->buf0.k1 (consumed P2)
    READA(1,0); READB(1,0); if (!last) STAGEPT(t0+2, 1, 0);
    BARR(); LGK0(); MFMACLU(); if (last) { VMWAIT(0); } else { VM2LP(); } BARR();
    // P4: tile t0+1 k1 ; stage (t0+3,k0)->buf1.k0 (consumed P3)
    READA(1,1); READB(1,1); if (!last) STAGEPT(t0+3, 0, 1);
    BARR(); LGK0(); MFMACLU(); if (!last) { VM2LP(); } BARR();
  }

  #pragma unroll
  for (int mi=0; mi<MREP; mi++)
    #pragma unroll
    for (int n=0; n<NF; n++)
      #pragma unroll
      for (int r=0;r<4;r++){
        int row = m0 + (wm*MREP+mi)*16 + g*4 + r;
        int col = n0 + wn*(NF*16) + n*16 + ln;
        C[(size_t)row*N + col] = acc[mi][n][r];
      }
  #undef AREG
  #undef BREG
  #undef STAGEPT
  #undef READA
  #undef READB
  #undef MFMACLU
  #undef BARR
  #undef LGK0
  #undef VM2LP
  #undef VM1LP
}

// ---------------- RMSNorm + RoPE + layout (1 wave per (s, head-slot) row) -----
__global__ __launch_bounds__(256) void norm_rope(const float* __restrict__ QKV,
                                                 const float* __restrict__ cosb,
                                                 const float* __restrict__ sinb,
                                                 const float* __restrict__ qw,
                                                 const float* __restrict__ kw,
                                                 u16* __restrict__ Qn,
                                                 u16* __restrict__ Kn,
                                                 u16* __restrict__ Vt){
  int w = threadIdx.x>>6, lane = threadIdx.x&63;
  int row = blockIdx.x*4 + w;              // 0 .. S*48-1
  int s = row / 48, slot = row - s*48;
  const float* src = QKV + (size_t)s*NQKV + slot*HD;
  float x0 = src[lane], x1 = src[lane+64];
  if (slot < 40){
    float ss = x0*x0 + x1*x1;
    #pragma unroll
    for (int off=1; off<64; off<<=1) ss += __shfl_xor(ss, off, 64);
    float r = rsqrtf(ss*(1.0f/128.0f) + 1e-6f);
    const float* wgt = (slot < 32) ? qw : kw;
    float y0 = x0*r*wgt[lane], y1 = x1*r*wgt[lane+64];
    float c0 = cosb[(size_t)s*HD+lane], c1 = cosb[(size_t)s*HD+lane+64];
    float s0 = sinb[(size_t)s*HD+lane], s1 = sinb[(size_t)s*HD+lane+64];
    float o0 = y0*c0 - y1*s0;
    float o1 = y1*c1 + y0*s1;
    float sc = (slot < 32) ? ATT_SCALE : 1.0f;
    u16* dst = (slot < 32) ? (Qn + ((size_t)slot*S_LEN + s)*HD)
                           : (Kn + ((size_t)(slot-32)*S_LEN + s)*HD);
    dst[lane]    = (u16)f2bfbits(o0*sc);
    dst[lane+64] = (u16)f2bfbits(o1*sc);
  } else {
    int kvh = slot - 40;
    u16* dst = Vt + (size_t)kvh*HD*S_LEN + s;
    dst[(size_t)lane*S_LEN]      = (u16)f2bfbits(x0);
    dst[(size_t)(lane+64)*S_LEN] = (u16)f2bfbits(x1);
  }
}

// ---------------- flash attention v4 (causal, GQA, balanced) ----------------
__global__ __launch_bounds__(256) void flash_attn(const u16* __restrict__ Qn,
                                                  const u16* __restrict__ Kn,
                                                  const u16* __restrict__ Vt,
                                                  u16* __restrict__ O){
  __shared__ u16 Ks[2][64*128];   // [kv][d] swizzled, 16KB each
  __shared__ u16 Vs[2][128*64];   // [d][kv] swizzled, 16KB each

  const int h = blockIdx.y;
  const int w = threadIdx.x>>6, lane = threadIdx.x&63, ln = lane&15, g = lane>>4;
  const int kvh = h>>2;                        // NH/NKV = 4
  const u16* Qh = Qn + (size_t)h*S_LEN*HD;
  const u16* Kh = Kn + (size_t)kvh*S_LEN*HD;
  const u16* Vh = Vt + (size_t)kvh*HD*S_LEN;

  const int krow_w = w*4 + g;
  const int ksw    = ((krow_w)&7)<<4;
  const int kcol   = ((ln*16) ^ ksw) >> 1;
  const int vrow_w = w*8 + (lane>>3);
  const int vsw    = ((lane>>3)&7)<<4;
  const int vcol   = (((lane&7)*16) ^ vsw) >> 1;

  #define STAGE(bufi, t) { \
    int kv0_ = (t)*64; \
    _Pragma("unroll") \
    for (int p=0;p<4;p++){ \
      const u16* ga = Kh + (size_t)(kv0_ + p*16 + krow_w)*HD + kcol; \
      GLOAD16(ga, (char*)&Ks[bufi][0] + p*4096 + w*1024); \
      const u16* gv = Vh + (size_t)(p*32 + vrow_w)*S_LEN + kv0_ + vcol; \
      GLOAD16(gv, (char*)&Vs[bufi][0] + p*4096 + w*1024); \
    } \
  }

  #pragma unroll 1
  for (int ph=0; ph<2; ph++){
    const int qb = ph ? (31 - blockIdx.x) : blockIdx.x;
    const int q0 = qb*64;
    const int qrow = q0 + w*16 + ln;

    short8 qf[4];
    #pragma unroll
    for (int c=0;c<4;c++)
      qf[c] = *(const short8*)(Qh + (size_t)qrow*HD + c*32 + g*8);

    f32x4 ot[8];
    #pragma unroll
    for (int dt=0;dt<8;dt++) ot[dt] = (f32x4){0.f,0.f,0.f,0.f};
    float m_run = -1e30f, l_run = 0.f;

    const int nt = qb + 1;

    STAGE(0, 0);
    __syncthreads();

    for (int t=0; t<nt; ++t){
      const int cur = t&1;
      if (t+1 < nt) STAGE(cur^1, t+1);
      const int kv0 = t*64;

      f32x4 st[4];
      #pragma unroll
      for (int mt=0; mt<4; mt++){
        f32x4 acc = (f32x4){0.f,0.f,0.f,0.f};
        #pragma unroll
        for (int c=0;c<4;c++){
          short8 kf = *(const short8*)((const char*)&Ks[cur][0]
                        + (mt*16+ln)*256 + ((c*64 + g*16) ^ ((ln&7)<<4)));
          acc = __builtin_amdgcn_mfma_f32_16x16x32_bf16(kf, qf[c], acc, 0,0,0);
        }
        st[mt] = acc;
      }

      float p[4][4];
      float mtile = -1e30f;
      if (t < qb){
        #pragma unroll
        for (int mt=0; mt<4; mt++)
          #pragma unroll
          for (int r=0;r<4;r++){
            p[mt][r] = st[mt][r];
            mtile = fmaxf(mtile, st[mt][r]);
          }
      } else {
        #pragma unroll
        for (int mt=0; mt<4; mt++)
          #pragma unroll
          for (int r=0;r<4;r++){
            int kv = kv0 + mt*16 + 4*g + r;
            float sv = (kv <= qrow) ? st[mt][r] : -1e30f;
            p[mt][r] = sv;
            mtile = fmaxf(mtile, sv);
          }
      }
      mtile = fmaxf(mtile, __shfl_xor(mtile, 16, 64));
      mtile = fmaxf(mtile, __shfl_xor(mtile, 32, 64));

      bool defer = __all(mtile <= m_run + 8.0f);
      float m_new = defer ? m_run : fmaxf(m_run, mtile);

      float l_tile = 0.f;
      #pragma unroll
      for (int mt=0; mt<4; mt++)
        #pragma unroll
        for (int r=0;r<4;r++){
          float e = exp2f((p[mt][r] - m_new)*LOG2E);
          p[mt][r] = e;
          l_tile += e;
        }
      l_tile += __shfl_xor(l_tile, 16, 64);
      l_tile += __shfl_xor(l_tile, 32, 64);
      if (defer){
        l_run += l_tile;
      } else {
        float alpha = exp2f((m_run - m_new)*LOG2E);
        l_run = l_run*alpha + l_tile;
        m_run = m_new;
        #pragma unroll
        for (int dt=0;dt<8;dt++) ot[dt] *= alpha;
      }

      short8 pf[2];
      #pragma unroll
      for (int ks2=0; ks2<2; ks2++){
        unsigned pk00 = cvtpk(p[2*ks2  ][0], p[2*ks2  ][1]);
        unsigned pk01 = cvtpk(p[2*ks2  ][2], p[2*ks2  ][3]);
        unsigned pk10 = cvtpk(p[2*ks2+1][0], p[2*ks2+1][1]);
        unsigned pk11 = cvtpk(p[2*ks2+1][2], p[2*ks2+1][3]);
        int src0 = (((2*g  )&3)<<4) | ln;
        int src1 = (((2*g+1)&3)<<4) | ln;
        unsigned t00 = (unsigned)__shfl((int)pk00, src0, 64);
        unsigned t10 = (unsigned)__shfl((int)pk10, src0, 64);
        unsigned t01 = (unsigned)__shfl((int)pk01, src0, 64);
        unsigned t11 = (unsigned)__shfl((int)pk11, src0, 64);
        unsigned u00 = (unsigned)__shfl((int)pk00, src1, 64);
        unsigned u10 = (unsigned)__shfl((int)pk10, src1, 64);
        unsigned u01 = (unsigned)__shfl((int)pk01, src1, 64);
        unsigned u11 = (unsigned)__shfl((int)pk11, src1, 64);
        bool hiv = (g >= 2);
        union { unsigned u[4]; short8 s; } pw;
        pw.u[0] = hiv ? t10 : t00;
        pw.u[1] = hiv ? t11 : t01;
        pw.u[2] = hiv ? u10 : u00;
        pw.u[3] = hiv ? u11 : u01;
        pf[ks2] = pw.s;
      }

      #pragma unroll
      for (int dt=0;dt<8;dt++){
        #pragma unroll
        for (int ks2=0; ks2<2; ks2++){
          short8 vf = *(const short8*)((const char*)&Vs[cur][0]
                        + (dt*16+ln)*128 + ((ks2*64 + g*16) ^ ((ln&7)<<4)));
          ot[dt] = __builtin_amdgcn_mfma_f32_16x16x32_bf16(vf, pf[ks2], ot[dt], 0,0,0);
        }
      }
      __syncthreads();
    }

    float inv = 1.0f / l_run;
    u16* orow = O + (size_t)qrow*(NH*HD) + h*HD;
    #pragma unroll
    for (int dt=0;dt<8;dt++){
      #pragma unroll
      for (int rr=0; rr<4; rr+=2){
        unsigned pkd = cvtpk(ot[dt][rr]*inv, ot[dt][rr+1]*inv);
        *(unsigned*)(orow + dt*16 + g*4 + rr) = pkd;
      }
    }
  }
  #undef STAGE
}

// ---------------- host ----------------
extern "C" void kernel_launch(void* const* d_in, const int* in_sizes, int n_in,
                              void* d_out, int out_size, void* d_ws, size_t ws_size,
                              hipStream_t stream){
  (void)in_sizes; (void)n_in; (void)out_size; (void)ws_size;
  const float* hs   = (const float*)d_in[0];
  const float* cosb = (const float*)d_in[1];
  const float* sinb = (const float*)d_in[2];
  const float* Wq   = (const float*)d_in[3];
  const float* Wk   = (const float*)d_in[4];
  const float* Wv   = (const float*)d_in[5];
  const float* Wo   = (const float*)d_in[6];
  const float* qw   = (const float*)d_in[7];
  const float* kw   = (const float*)d_in[8];
  float* out = (float*)d_out;

  char* ws = (char*)d_ws;
  u16*   Xb    = (u16*)  (ws);
  u16*   WQKV  = (u16*)  (ws + 16777216);
  float* QKV   = (float*)(ws + 67108864);
  u16*   attnB = (u16*)  (ws + 67108864);   // overlay: QKV dead after norm_rope
  u16*   Qn    = (u16*)  (ws + 117440512);
  u16*   Kn    = (u16*)  (ws + 134217728);
  u16*   Vt    = (u16*)  (ws + 138412032);
  u16*   Wob   = WQKV;                      // overlay: WQKV dead after GEMM1

  cvt_bf16<<<(S_LEN*HIDD/8)/256, 256, 0, stream>>>(hs, Xb, S_LEN*HIDD/8);
  cvt_bf16<<<(NH*HD*HIDD/8)/256, 256, 0, stream>>>(Wq, WQKV, NH*HD*HIDD/8);
  cvt_bf16<<<(NKV*HD*HIDD/8)/256, 256, 0, stream>>>(Wk, WQKV + (size_t)NH*HD*HIDD, NKV*HD*HIDD/8);
  cvt_bf16<<<(NKV*HD*HIDD/8)/256, 256, 0, stream>>>(Wv, WQKV + (size_t)(NH+NKV)*HD*HIDD, NKV*HD*HIDD/8);
  // GEMM1: [2048 x 4096] x [6144 x 4096]^T, 256x192 tiles -> 8x32 = 256 blocks
  gemm_4ph<256,192><<<256, 512, 0, stream>>>(Xb, WQKV, QKV, NQKV, HIDD, NQKV/192);
  norm_rope<<<(S_LEN*48)/4, 256, 0, stream>>>(QKV, cosb, sinb, qw, kw, Qn, Kn, Vt);
  cvt_bf16<<<(HIDD*NH*HD/8)/256, 256, 0, stream>>>(Wo, Wob, HIDD*NH*HD/8);
  // flash attention: 16 complementary pairs x 32 heads = 512 blocks
  flash_attn<<<dim3(16, NH), 256, 0, stream>>>(Qn, Kn, Vt, attnB);
  // GEMM2: [2048 x 4096] x [4096 x 4096]^T, 128x256 tiles -> 16x16 = 256 blocks
  gemm_4ph<128,256><<<256, 512, 0, stream>>>(attnB, Wob, out, HIDD, HIDD, HIDD/256);
}

// Round 9
// 332.692 us; speedup vs baseline: 1.8301x; 1.0284x over previous
//
#include <hip/hip_runtime.h>
#include <hip/hip_bf16.h>
#include <stdint.h>

#define S_LEN 2048
#define HIDD  4096
#define NH    32
#define NKV   8
#define HD    128
#define NQKV  6144   // (NH + 2*NKV) * HD
#define ATT_SCALE 0.08838834764831845f
#define LOG2E 1.4426950408889634f

typedef unsigned short u16;
typedef __attribute__((ext_vector_type(8))) short short8;
typedef __attribute__((ext_vector_type(4))) float f32x4;

__device__ __forceinline__ unsigned f2bfbits(float f){
  union{float f; unsigned u;} v; v.f = f;
  return (v.u + 0x7FFFu + ((v.u>>16)&1u)) >> 16;
}
__device__ __forceinline__ unsigned packbf(float a, float b){
  return f2bfbits(a) | (f2bfbits(b)<<16);
}
__device__ __forceinline__ unsigned cvtpk(float lo, float hi){
  unsigned r;
  asm("v_cvt_pk_bf16_f32 %0, %1, %2" : "=v"(r) : "v"(lo), "v"(hi));
  return r;
}

#define GLOAD16(g, l) __builtin_amdgcn_global_load_lds( \
    (__attribute__((address_space(1))) void*)(g), \
    (__attribute__((address_space(3))) void*)(l), 16, 0, 0)

#define VMWAIT(n) asm volatile("s_waitcnt vmcnt(" #n ")" ::: "memory")
#define SCHED0() __builtin_amdgcn_sched_barrier(0)

// ---------------- fp32 -> bf16 convert, 4 segments in one launch -------------
__global__ __launch_bounds__(256) void cvt_all(const float* __restrict__ hs,
                                               const float* __restrict__ Wq,
                                               const float* __restrict__ Wk,
                                               const float* __restrict__ Wv,
                                               u16* __restrict__ Xb,
                                               u16* __restrict__ WQKV){
  const float* src; u16* dst; int n8;
  switch (blockIdx.y){
    case 0: src = hs; dst = Xb;                        n8 = S_LEN*HIDD/8;    break;
    case 1: src = Wq; dst = WQKV;                      n8 = NH*HD*HIDD/8;    break;
    case 2: src = Wk; dst = WQKV + (size_t)NH*HD*HIDD; n8 = NKV*HD*HIDD/8;   break;
    default:src = Wv; dst = WQKV + (size_t)(NH+NKV)*HD*HIDD; n8 = NKV*HD*HIDD/8; break;
  }
  int i = blockIdx.x*256 + threadIdx.x;
  if (i >= n8) return;
  const float4* p = (const float4*)src;
  float4 a = p[2*i], b = p[2*i+1];
  union { unsigned u[4]; short8 s; } o;
  o.u[0] = packbf(a.x, a.y); o.u[1] = packbf(a.z, a.w);
  o.u[2] = packbf(b.x, b.y); o.u[3] = packbf(b.z, b.w);
  *(short8*)(dst + (size_t)i*8) = o.s;
}

__global__ __launch_bounds__(256) void cvt_bf16(const float* __restrict__ in,
                                                u16* __restrict__ out, int n8){
  int i = blockIdx.x*256 + threadIdx.x;
  if (i >= n8) return;
  const float4* p = (const float4*)in;
  float4 a = p[2*i], b = p[2*i+1];
  union { unsigned u[4]; short8 s; } o;
  o.u[0] = packbf(a.x, a.y); o.u[1] = packbf(a.z, a.w);
  o.u[2] = packbf(b.x, b.y); o.u[3] = packbf(b.z, b.w);
  *(short8*)(out + (size_t)i*8) = o.s;
}

// ============ 4-phase pipelined bf16 GEMM, C = A * B^T (fp32 C) =============
// One barrier per phase; NO hard lgkmcnt fence before MFMA -> compiler emits
// fine-grained lgkmcnt(N) interleaving ds_read completion with MFMA issue.
// sched_barrier(0) before VMWAIT pins MFMAs above the closing barrier (WAR
// safety: phase-p reads are consumed before the barrier that precedes the
// p+1 re-stage of the same region). vmcnt ledger identical to round 8.
template<int BM, int BN>
__global__ __launch_bounds__(512) void gemm_4ph(const u16* __restrict__ A,
                                                const u16* __restrict__ B,
                                                float* __restrict__ C,
                                                int N, int K, int nbx){
  constexpr int MREP = BM/32;     // m-frags per wave (8 | 4)
  constexpr int NF   = BN/64;     // n-frags per wave (3 | 4)
  constexpr int AH   = BM/128;    // 16KB halves per A k-half region (2 | 1)
  constexpr int ASZ  = BM*64;     // bytes per (buf,khalf) A region
  __shared__ __align__(16) char lds[4*ASZ + 65536];

  const int tid = threadIdx.x;
  const int w = tid>>6, lane = tid&63, ln = lane&15, g = lane>>4;
  const int wm = w>>2, wn = w&3;
  const int swz5 = ((ln>>3)&1)<<5;

  const int nwg = gridDim.x, flat = blockIdx.x;
  const int wg = (flat&7)*(nwg>>3) + (flat>>3);
  const int by = wg/nbx, bx = wg - by*nbx;
  const int m0 = by*BM, n0 = bx*BN;

  const int rs   = ((tid>>6)<<4) + ((tid&63)>>2);
  const int ksrc = ((tid&3)<<3) ^ (((tid>>5)&1)<<4);
  const u16* srcA[AH];
  #pragma unroll
  for (int h=0;h<AH;h++) srcA[h] = A + (size_t)(m0 + h*128 + rs)*K + ksrc;
  const u16* srcB[2];
  #pragma unroll
  for (int h=0;h<2;h++)  srcB[h] = B + (size_t)(n0 + h*128 + rs)*K + ksrc;

  #define AREG(bf,kh) (lds + ((bf)*2 + (kh))*ASZ)
  #define BREG(bf,kh) (lds + 4*ASZ + ((bf)*2 + (kh))*16384)

  #define STAGEPT(t, kh, bf) { const int off_ = (t)*64 + (kh)*32;                 \
    _Pragma("unroll") for (int h=0;h<AH;h++)                                      \
      GLOAD16(srcA[h]+off_, AREG(bf,kh) + h*8192 + w*1024);                       \
    _Pragma("unroll") for (int h=0;h<2;h++)                                       \
      GLOAD16(srcB[h]+off_, BREG(bf,kh) + h*8192 + w*1024); }

  f32x4 acc[MREP][NF];
  #pragma unroll
  for (int m=0;m<MREP;m++)
    #pragma unroll
    for (int n=0;n<NF;n++) acc[m][n] = (f32x4){0.f,0.f,0.f,0.f};
  short8 a_[MREP], b_[NF];

  #define READA(bf,kh) { _Pragma("unroll") for (int m=0;m<MREP;m++)               \
    a_[m] = *(const short8*)(AREG(bf,kh) + (wm*MREP+m)*1024 + ln*64 + ((g*16)^swz5)); }
  #define READB(bf,kh) { _Pragma("unroll") for (int n=0;n<NF;n++)                 \
    b_[n] = *(const short8*)(BREG(bf,kh) + (wn*NF+n)*1024 + ln*64 + ((g*16)^swz5)); }
  #define MFMACLU() { __builtin_amdgcn_s_setprio(1);                              \
    _Pragma("unroll") for (int m=0;m<MREP;m++)                                    \
      _Pragma("unroll") for (int n=0;n<NF;n++)                                    \
        acc[m][n] = __builtin_amdgcn_mfma_f32_16x16x32_bf16(a_[m], b_[n], acc[m][n], 0,0,0); \
    __builtin_amdgcn_s_setprio(0); }
  #define BARR() __builtin_amdgcn_s_barrier()
  #define VM2LP() do{ if constexpr (AH==2) { VMWAIT(8); } else { VMWAIT(6); } }while(0)
  #define VM1LP() do{ if constexpr (AH==2) { VMWAIT(4); } else { VMWAIT(3); } }while(0)

  // prologue: tile0 both halves, tile1 k0
  STAGEPT(0,0,0); STAGEPT(0,1,0); STAGEPT(1,0,1);
  VMWAIT(0); BARR(); SCHED0();

  const int NIT = K>>7;   // 2 K64-tiles per iteration
  #pragma unroll 1
  for (int it=0; it<NIT; ++it){
    const bool last = (it == NIT-1);
    const int t0 = 2*it;
    // P1: tile t0 k0 ; stage (t0+1,k1)->buf1.k1 (consumed prev-iter P4)
    READA(0,0); READB(0,0); STAGEPT(t0+1, 1, 1);
    MFMACLU();
    SCHED0(); VM2LP(); BARR(); SCHED0();
    // P2: tile t0 k1 ; stage (t0+2,k0)->buf0.k0 (consumed P1)
    READA(0,1); READB(0,1); if (!last) STAGEPT(t0+2, 0, 0);
    MFMACLU();
    SCHED0(); if (last) { VM1LP(); } else { VM2LP(); } BARR(); SCHED0();
    // P3: tile t0+1 k0 ; stage (t0+2,k1)->buf0.k1 (consumed P2)
    READA(1,0); READB(1,0); if (!last) STAGEPT(t0+2, 1, 0);
    MFMACLU();
    SCHED0(); if (last) { VMWAIT(0); } else { VM2LP(); } BARR(); SCHED0();
    // P4: tile t0+1 k1 ; stage (t0+3,k0)->buf1.k0 (consumed P3)
    READA(1,1); READB(1,1); if (!last) STAGEPT(t0+3, 0, 1);
    MFMACLU();
    SCHED0(); if (!last) { VM2LP(); } BARR(); SCHED0();
  }

  #pragma unroll
  for (int mi=0; mi<MREP; mi++)
    #pragma unroll
    for (int n=0; n<NF; n++)
      #pragma unroll
      for (int r=0;r<4;r++){
        int row = m0 + (wm*MREP+mi)*16 + g*4 + r;
        int col = n0 + wn*(NF*16) + n*16 + ln;
        C[(size_t)row*N + col] = acc[mi][n][r];
      }
  #undef AREG
  #undef BREG
  #undef STAGEPT
  #undef READA
  #undef READB
  #undef MFMACLU
  #undef BARR
  #undef VM2LP
  #undef VM1LP
}

// ---------------- RMSNorm + RoPE + layout (1 wave per (s, head-slot) row) -----
__global__ __launch_bounds__(256) void norm_rope(const float* __restrict__ QKV,
                                                 const float* __restrict__ cosb,
                                                 const float* __restrict__ sinb,
                                                 const float* __restrict__ qw,
                                                 const float* __restrict__ kw,
                                                 u16* __restrict__ Qn,
                                                 u16* __restrict__ Kn,
                                                 u16* __restrict__ Vt){
  int w = threadIdx.x>>6, lane = threadIdx.x&63;
  int row = blockIdx.x*4 + w;              // 0 .. S*48-1
  int s = row / 48, slot = row - s*48;
  const float* src = QKV + (size_t)s*NQKV + slot*HD;
  float x0 = src[lane], x1 = src[lane+64];
  if (slot < 40){
    float ss = x0*x0 + x1*x1;
    #pragma unroll
    for (int off=1; off<64; off<<=1) ss += __shfl_xor(ss, off, 64);
    float r = rsqrtf(ss*(1.0f/128.0f) + 1e-6f);
    const float* wgt = (slot < 32) ? qw : kw;
    float y0 = x0*r*wgt[lane], y1 = x1*r*wgt[lane+64];
    float c0 = cosb[(size_t)s*HD+lane], c1 = cosb[(size_t)s*HD+lane+64];
    float s0 = sinb[(size_t)s*HD+lane], s1 = sinb[(size_t)s*HD+lane+64];
    float o0 = y0*c0 - y1*s0;
    float o1 = y1*c1 + y0*s1;
    float sc = (slot < 32) ? ATT_SCALE : 1.0f;
    u16* dst = (slot < 32) ? (Qn + ((size_t)slot*S_LEN + s)*HD)
                           : (Kn + ((size_t)(slot-32)*S_LEN + s)*HD);
    dst[lane]    = (u16)f2bfbits(o0*sc);
    dst[lane+64] = (u16)f2bfbits(o1*sc);
  } else {
    int kvh = slot - 40;
    u16* dst = Vt + (size_t)kvh*HD*S_LEN + s;
    dst[(size_t)lane*S_LEN]      = (u16)f2bfbits(x0);
    dst[(size_t)(lane+64)*S_LEN] = (u16)f2bfbits(x1);
  }
}

// ---------------- flash attention v4 (causal, GQA, balanced) ----------------
__global__ __launch_bounds__(256) void flash_attn(const u16* __restrict__ Qn,
                                                  const u16* __restrict__ Kn,
                                                  const u16* __restrict__ Vt,
                                                  u16* __restrict__ O){
  __shared__ u16 Ks[2][64*128];   // [kv][d] swizzled, 16KB each
  __shared__ u16 Vs[2][128*64];   // [d][kv] swizzled, 16KB each

  const int h = blockIdx.y;
  const int w = threadIdx.x>>6, lane = threadIdx.x&63, ln = lane&15, g = lane>>4;
  const int kvh = h>>2;                        // NH/NKV = 4
  const u16* Qh = Qn + (size_t)h*S_LEN*HD;
  const u16* Kh = Kn + (size_t)kvh*S_LEN*HD;
  const u16* Vh = Vt + (size_t)kvh*HD*S_LEN;

  const int krow_w = w*4 + g;
  const int ksw    = ((krow_w)&7)<<4;
  const int kcol   = ((ln*16) ^ ksw) >> 1;
  const int vrow_w = w*8 + (lane>>3);
  const int vsw    = ((lane>>3)&7)<<4;
  const int vcol   = (((lane&7)*16) ^ vsw) >> 1;

  #define STAGE(bufi, t) { \
    int kv0_ = (t)*64; \
    _Pragma("unroll") \
    for (int p=0;p<4;p++){ \
      const u16* ga = Kh + (size_t)(kv0_ + p*16 + krow_w)*HD + kcol; \
      GLOAD16(ga, (char*)&Ks[bufi][0] + p*4096 + w*1024); \
      const u16* gv = Vh + (size_t)(p*32 + vrow_w)*S_LEN + kv0_ + vcol; \
      GLOAD16(gv, (char*)&Vs[bufi][0] + p*4096 + w*1024); \
    } \
  }

  #pragma unroll 1
  for (int ph=0; ph<2; ph++){
    const int qb = ph ? (31 - blockIdx.x) : blockIdx.x;
    const int q0 = qb*64;
    const int qrow = q0 + w*16 + ln;

    short8 qf[4];
    #pragma unroll
    for (int c=0;c<4;c++)
      qf[c] = *(const short8*)(Qh + (size_t)qrow*HD + c*32 + g*8);

    f32x4 ot[8];
    #pragma unroll
    for (int dt=0;dt<8;dt++) ot[dt] = (f32x4){0.f,0.f,0.f,0.f};
    float m_run = -1e30f, l_run = 0.f;

    const int nt = qb + 1;

    STAGE(0, 0);
    __syncthreads();

    for (int t=0; t<nt; ++t){
      const int cur = t&1;
      if (t+1 < nt) STAGE(cur^1, t+1);
      const int kv0 = t*64;

      f32x4 st[4];
      #pragma unroll
      for (int mt=0; mt<4; mt++){
        f32x4 acc = (f32x4){0.f,0.f,0.f,0.f};
        #pragma unroll
        for (int c=0;c<4;c++){
          short8 kf = *(const short8*)((const char*)&Ks[cur][0]
                        + (mt*16+ln)*256 + ((c*64 + g*16) ^ ((ln&7)<<4)));
          acc = __builtin_amdgcn_mfma_f32_16x16x32_bf16(kf, qf[c], acc, 0,0,0);
        }
        st[mt] = acc;
      }

      float p[4][4];
      float mtile = -1e30f;
      if (t < qb){
        #pragma unroll
        for (int mt=0; mt<4; mt++)
          #pragma unroll
          for (int r=0;r<4;r++){
            p[mt][r] = st[mt][r];
            mtile = fmaxf(mtile, st[mt][r]);
          }
      } else {
        #pragma unroll
        for (int mt=0; mt<4; mt++)
          #pragma unroll
          for (int r=0;r<4;r++){
            int kv = kv0 + mt*16 + 4*g + r;
            float sv = (kv <= qrow) ? st[mt][r] : -1e30f;
            p[mt][r] = sv;
            mtile = fmaxf(mtile, sv);
          }
      }
      mtile = fmaxf(mtile, __shfl_xor(mtile, 16, 64));
      mtile = fmaxf(mtile, __shfl_xor(mtile, 32, 64));

      bool defer = __all(mtile <= m_run + 8.0f);
      float m_new = defer ? m_run : fmaxf(m_run, mtile);

      float l_tile = 0.f;
      #pragma unroll
      for (int mt=0; mt<4; mt++)
        #pragma unroll
        for (int r=0;r<4;r++){
          float e = exp2f((p[mt][r] - m_new)*LOG2E);
          p[mt][r] = e;
          l_tile += e;
        }
      l_tile += __shfl_xor(l_tile, 16, 64);
      l_tile += __shfl_xor(l_tile, 32, 64);
      if (defer){
        l_run += l_tile;
      } else {
        float alpha = exp2f((m_run - m_new)*LOG2E);
        l_run = l_run*alpha + l_tile;
        m_run = m_new;
        #pragma unroll
        for (int dt=0;dt<8;dt++) ot[dt] *= alpha;
      }

      short8 pf[2];
      #pragma unroll
      for (int ks2=0; ks2<2; ks2++){
        unsigned pk00 = cvtpk(p[2*ks2  ][0], p[2*ks2  ][1]);
        unsigned pk01 = cvtpk(p[2*ks2  ][2], p[2*ks2  ][3]);
        unsigned pk10 = cvtpk(p[2*ks2+1][0], p[2*ks2+1][1]);
        unsigned pk11 = cvtpk(p[2*ks2+1][2], p[2*ks2+1][3]);
        int src0 = (((2*g  )&3)<<4) | ln;
        int src1 = (((2*g+1)&3)<<4) | ln;
        unsigned t00 = (unsigned)__shfl((int)pk00, src0, 64);
        unsigned t10 = (unsigned)__shfl((int)pk10, src0, 64);
        unsigned t01 = (unsigned)__shfl((int)pk01, src0, 64);
        unsigned t11 = (unsigned)__shfl((int)pk11, src0, 64);
        unsigned u00 = (unsigned)__shfl((int)pk00, src1, 64);
        unsigned u10 = (unsigned)__shfl((int)pk10, src1, 64);
        unsigned u01 = (unsigned)__shfl((int)pk01, src1, 64);
        unsigned u11 = (unsigned)__shfl((int)pk11, src1, 64);
        bool hiv = (g >= 2);
        union { unsigned u[4]; short8 s; } pw;
        pw.u[0] = hiv ? t10 : t00;
        pw.u[1] = hiv ? t11 : t01;
        pw.u[2] = hiv ? u10 : u00;
        pw.u[3] = hiv ? u11 : u01;
        pf[ks2] = pw.s;
      }

      #pragma unroll
      for (int dt=0;dt<8;dt++){
        #pragma unroll
        for (int ks2=0; ks2<2; ks2++){
          short8 vf = *(const short8*)((const char*)&Vs[cur][0]
                        + (dt*16+ln)*128 + ((ks2*64 + g*16) ^ ((ln&7)<<4)));
          ot[dt] = __builtin_amdgcn_mfma_f32_16x16x32_bf16(vf, pf[ks2], ot[dt], 0,0,0);
        }
      }
      __syncthreads();
    }

    float inv = 1.0f / l_run;
    u16* orow = O + (size_t)qrow*(NH*HD) + h*HD;
    #pragma unroll
    for (int dt=0;dt<8;dt++){
      #pragma unroll
      for (int rr=0; rr<4; rr+=2){
        unsigned pkd = cvtpk(ot[dt][rr]*inv, ot[dt][rr+1]*inv);
        *(unsigned*)(orow + dt*16 + g*4 + rr) = pkd;
      }
    }
  }
  #undef STAGE
}

// ---------------- host ----------------
extern "C" void kernel_launch(void* const* d_in, const int* in_sizes, int n_in,
                              void* d_out, int out_size, void* d_ws, size_t ws_size,
                              hipStream_t stream){
  (void)in_sizes; (void)n_in; (void)out_size; (void)ws_size;
  const float* hs   = (const float*)d_in[0];
  const float* cosb = (const float*)d_in[1];
  const float* sinb = (const float*)d_in[2];
  const float* Wq   = (const float*)d_in[3];
  const float* Wk   = (const float*)d_in[4];
  const float* Wv   = (const float*)d_in[5];
  const float* Wo   = (const float*)d_in[6];
  const float* qw   = (const float*)d_in[7];
  const float* kw   = (const float*)d_in[8];
  float* out = (float*)d_out;

  char* ws = (char*)d_ws;
  u16*   Xb    = (u16*)  (ws);
  u16*   WQKV  = (u16*)  (ws + 16777216);
  float* QKV   = (float*)(ws + 67108864);
  u16*   attnB = (u16*)  (ws + 67108864);   // overlay: QKV dead after norm_rope
  u16*   Qn    = (u16*)  (ws + 117440512);
  u16*   Kn    = (u16*)  (ws + 134217728);
  u16*   Vt    = (u16*)  (ws + 138412032);
  u16*   Wob   = WQKV;                      // overlay: WQKV dead after GEMM1

  // 1. convert X + Wq|Wk|Wv in one launch (4 segments)
  cvt_all<<<dim3(8192, 4), 256, 0, stream>>>(hs, Wq, Wk, Wv, Xb, WQKV);
  // 2. GEMM1: [2048 x 4096] x [6144 x 4096]^T, 256x192 tiles -> 256 blocks
  gemm_4ph<256,192><<<256, 512, 0, stream>>>(Xb, WQKV, QKV, NQKV, HIDD, NQKV/192);
  // 3. RMSNorm + RoPE + relayout
  norm_rope<<<(S_LEN*48)/4, 256, 0, stream>>>(QKV, cosb, sinb, qw, kw, Qn, Kn, Vt);
  // 4. convert Wo into the now-dead WQKV region
  cvt_bf16<<<(HIDD*NH*HD/8)/256, 256, 0, stream>>>(Wo, Wob, HIDD*NH*HD/8);
  // 5. flash attention: 16 complementary pairs x 32 heads = 512 blocks
  flash_attn<<<dim3(16, NH), 256, 0, stream>>>(Qn, Kn, Vt, attnB);
  // 6. GEMM2: [2048 x 4096] x [4096 x 4096]^T, 128x256 tiles -> 256 blocks
  gemm_4ph<128,256><<<256, 512, 0, stream>>>(attnB, Wob, out, HIDD, HIDD, HIDD/256);
}

// Round 10
// 329.958 us; speedup vs baseline: 1.8452x; 1.0083x over previous
//
#include <hip/hip_runtime.h>
#include <hip/hip_bf16.h>
#include <stdint.h>

#define S_LEN 2048
#define HIDD  4096
#define NH    32
#define NKV   8
#define HD    128
#define NQKV  6144   // (NH + 2*NKV) * HD
#define ATT_SCALE 0.08838834764831845f
#define LOG2E 1.4426950408889634f

typedef unsigned short u16;
typedef __attribute__((ext_vector_type(8))) short short8;
typedef __attribute__((ext_vector_type(4))) float f32x4;

__device__ __forceinline__ unsigned f2bfbits(float f){
  union{float f; unsigned u;} v; v.f = f;
  return (v.u + 0x7FFFu + ((v.u>>16)&1u)) >> 16;
}
__device__ __forceinline__ float bf2f(u16 b){
  union{unsigned u; float f;} v; v.u = ((unsigned)b)<<16;
  return v.f;
}
__device__ __forceinline__ unsigned packbf(float a, float b){
  return f2bfbits(a) | (f2bfbits(b)<<16);
}
__device__ __forceinline__ unsigned cvtpk(float lo, float hi){
  unsigned r;
  asm("v_cvt_pk_bf16_f32 %0, %1, %2" : "=v"(r) : "v"(lo), "v"(hi));
  return r;
}

#define GLOAD16(g, l) __builtin_amdgcn_global_load_lds( \
    (__attribute__((address_space(1))) void*)(g), \
    (__attribute__((address_space(3))) void*)(l), 16, 0, 0)

#define VMWAIT(n) asm volatile("s_waitcnt vmcnt(" #n ")" ::: "memory")
#define SCHED0() __builtin_amdgcn_sched_barrier(0)

// ---------------- fp32 -> bf16 convert, 4 segments in one launch -------------
__global__ __launch_bounds__(256) void cvt_all(const float* __restrict__ hs,
                                               const float* __restrict__ Wq,
                                               const float* __restrict__ Wk,
                                               const float* __restrict__ Wv,
                                               u16* __restrict__ Xb,
                                               u16* __restrict__ WQKV){
  const float* src; u16* dst; int n8;
  switch (blockIdx.y){
    case 0: src = hs; dst = Xb;                        n8 = S_LEN*HIDD/8;    break;
    case 1: src = Wq; dst = WQKV;                      n8 = NH*HD*HIDD/8;    break;
    case 2: src = Wk; dst = WQKV + (size_t)NH*HD*HIDD; n8 = NKV*HD*HIDD/8;   break;
    default:src = Wv; dst = WQKV + (size_t)(NH+NKV)*HD*HIDD; n8 = NKV*HD*HIDD/8; break;
  }
  int i = blockIdx.x*256 + threadIdx.x;
  if (i >= n8) return;
  const float4* p = (const float4*)src;
  float4 a = p[2*i], b = p[2*i+1];
  union { unsigned u[4]; short8 s; } o;
  o.u[0] = packbf(a.x, a.y); o.u[1] = packbf(a.z, a.w);
  o.u[2] = packbf(b.x, b.y); o.u[3] = packbf(b.z, b.w);
  *(short8*)(dst + (size_t)i*8) = o.s;
}

__global__ __launch_bounds__(256) void cvt_bf16(const float* __restrict__ in,
                                                u16* __restrict__ out, int n8){
  int i = blockIdx.x*256 + threadIdx.x;
  if (i >= n8) return;
  const float4* p = (const float4*)in;
  float4 a = p[2*i], b = p[2*i+1];
  union { unsigned u[4]; short8 s; } o;
  o.u[0] = packbf(a.x, a.y); o.u[1] = packbf(a.z, a.w);
  o.u[2] = packbf(b.x, b.y); o.u[3] = packbf(b.z, b.w);
  *(short8*)(out + (size_t)i*8) = o.s;
}

// ============ 4-phase pipelined bf16 GEMM, C = A * B^T ======================
// OT = float (fp32 C) or u16 (bf16 C). One barrier per phase; compiler-
// scheduled fine lgkmcnt between ds_read and MFMA; counted vmcnt ledger
// identical to round 8/9. READB issued before READA so the first MFMA's
// operands land earliest.
template<int BM, int BN, typename OT>
__global__ __launch_bounds__(512) void gemm_4ph(const u16* __restrict__ A,
                                                const u16* __restrict__ B,
                                                OT* __restrict__ C,
                                                int N, int K, int nbx){
  constexpr int MREP = BM/32;
  constexpr int NF   = BN/64;
  constexpr int AH   = BM/128;
  constexpr int ASZ  = BM*64;
  __shared__ __align__(16) char lds[4*ASZ + 65536];

  const int tid = threadIdx.x;
  const int w = tid>>6, lane = tid&63, ln = lane&15, g = lane>>4;
  const int wm = w>>2, wn = w&3;
  const int swz5 = ((ln>>3)&1)<<5;

  const int nwg = gridDim.x, flat = blockIdx.x;
  const int wg = (flat&7)*(nwg>>3) + (flat>>3);
  const int by = wg/nbx, bx = wg - by*nbx;
  const int m0 = by*BM, n0 = bx*BN;

  const int rs   = ((tid>>6)<<4) + ((tid&63)>>2);
  const int ksrc = ((tid&3)<<3) ^ (((tid>>5)&1)<<4);
  const u16* srcA[AH];
  #pragma unroll
  for (int h=0;h<AH;h++) srcA[h] = A + (size_t)(m0 + h*128 + rs)*K + ksrc;
  const u16* srcB[2];
  #pragma unroll
  for (int h=0;h<2;h++)  srcB[h] = B + (size_t)(n0 + h*128 + rs)*K + ksrc;

  #define AREG(bf,kh) (lds + ((bf)*2 + (kh))*ASZ)
  #define BREG(bf,kh) (lds + 4*ASZ + ((bf)*2 + (kh))*16384)

  #define STAGEPT(t, kh, bf) { const int off_ = (t)*64 + (kh)*32;                 \
    _Pragma("unroll") for (int h=0;h<AH;h++)                                      \
      GLOAD16(srcA[h]+off_, AREG(bf,kh) + h*8192 + w*1024);                       \
    _Pragma("unroll") for (int h=0;h<2;h++)                                       \
      GLOAD16(srcB[h]+off_, BREG(bf,kh) + h*8192 + w*1024); }

  f32x4 acc[MREP][NF];
  #pragma unroll
  for (int m=0;m<MREP;m++)
    #pragma unroll
    for (int n=0;n<NF;n++) acc[m][n] = (f32x4){0.f,0.f,0.f,0.f};
  short8 a_[MREP], b_[NF];

  #define READA(bf,kh) { _Pragma("unroll") for (int m=0;m<MREP;m++)               \
    a_[m] = *(const short8*)(AREG(bf,kh) + (wm*MREP+m)*1024 + ln*64 + ((g*16)^swz5)); }
  #define READB(bf,kh) { _Pragma("unroll") for (int n=0;n<NF;n++)                 \
    b_[n] = *(const short8*)(BREG(bf,kh) + (wn*NF+n)*1024 + ln*64 + ((g*16)^swz5)); }
  #define MFMACLU() { __builtin_amdgcn_s_setprio(1);                              \
    _Pragma("unroll") for (int m=0;m<MREP;m++)                                    \
      _Pragma("unroll") for (int n=0;n<NF;n++)                                    \
        acc[m][n] = __builtin_amdgcn_mfma_f32_16x16x32_bf16(a_[m], b_[n], acc[m][n], 0,0,0); \
    __builtin_amdgcn_s_setprio(0); }
  #define BARR() __builtin_amdgcn_s_barrier()
  #define VM2LP() do{ if constexpr (AH==2) { VMWAIT(8); } else { VMWAIT(6); } }while(0)
  #define VM1LP() do{ if constexpr (AH==2) { VMWAIT(4); } else { VMWAIT(3); } }while(0)

  // prologue: tile0 both halves, tile1 k0
  STAGEPT(0,0,0); STAGEPT(0,1,0); STAGEPT(1,0,1);
  VMWAIT(0); BARR(); SCHED0();

  const int NIT = K>>7;   // 2 K64-tiles per iteration
  #pragma unroll 1
  for (int it=0; it<NIT; ++it){
    const bool last = (it == NIT-1);
    const int t0 = 2*it;
    // P1: tile t0 k0 ; stage (t0+1,k1)->buf1.k1 (consumed prev-iter P4)
    READB(0,0); READA(0,0); STAGEPT(t0+1, 1, 1);
    MFMACLU();
    SCHED0(); VM2LP(); BARR(); SCHED0();
    // P2: tile t0 k1 ; stage (t0+2,k0)->buf0.k0 (consumed P1)
    READB(0,1); READA(0,1); if (!last) STAGEPT(t0+2, 0, 0);
    MFMACLU();
    SCHED0(); if (last) { VM1LP(); } else { VM2LP(); } BARR(); SCHED0();
    // P3: tile t0+1 k0 ; stage (t0+2,k1)->buf0.k1 (consumed P2)
    READB(1,0); READA(1,0); if (!last) STAGEPT(t0+2, 1, 0);
    MFMACLU();
    SCHED0(); if (last) { VMWAIT(0); } else { VM2LP(); } BARR(); SCHED0();
    // P4: tile t0+1 k1 ; stage (t0+3,k0)->buf1.k0 (consumed P3)
    READB(1,1); READA(1,1); if (!last) STAGEPT(t0+3, 0, 1);
    MFMACLU();
    SCHED0(); if (!last) { VM2LP(); } BARR(); SCHED0();
  }

  #pragma unroll
  for (int mi=0; mi<MREP; mi++)
    #pragma unroll
    for (int n=0; n<NF; n++)
      #pragma unroll
      for (int r=0;r<4;r++){
        int row = m0 + (wm*MREP+mi)*16 + g*4 + r;
        int col = n0 + wn*(NF*16) + n*16 + ln;
        if constexpr (__is_same(OT, u16))
          C[(size_t)row*N + col] = (u16)f2bfbits(acc[mi][n][r]);
        else
          C[(size_t)row*N + col] = acc[mi][n][r];
      }
  #undef AREG
  #undef BREG
  #undef STAGEPT
  #undef READA
  #undef READB
  #undef MFMACLU
  #undef BARR
  #undef VM2LP
  #undef VM1LP
}

// ---------------- RMSNorm + RoPE + layout (bf16 QKV input) -------------------
// Q gets ATT_SCALE*LOG2E folded in (attn computes exp2 directly).
__global__ __launch_bounds__(256) void norm_rope(const u16* __restrict__ QKVb,
                                                 const float* __restrict__ cosb,
                                                 const float* __restrict__ sinb,
                                                 const float* __restrict__ qw,
                                                 const float* __restrict__ kw,
                                                 u16* __restrict__ Qn,
                                                 u16* __restrict__ Kn,
                                                 u16* __restrict__ Vt){
  int w = threadIdx.x>>6, lane = threadIdx.x&63;
  int row = blockIdx.x*4 + w;              // 0 .. S*48-1
  int s = row / 48, slot = row - s*48;
  const u16* src = QKVb + (size_t)s*NQKV + slot*HD;
  float x0 = bf2f(src[lane]), x1 = bf2f(src[lane+64]);
  if (slot < 40){
    float ss = x0*x0 + x1*x1;
    #pragma unroll
    for (int off=1; off<64; off<<=1) ss += __shfl_xor(ss, off, 64);
    float r = rsqrtf(ss*(1.0f/128.0f) + 1e-6f);
    const float* wgt = (slot < 32) ? qw : kw;
    float y0 = x0*r*wgt[lane], y1 = x1*r*wgt[lane+64];
    float c0 = cosb[(size_t)s*HD+lane], c1 = cosb[(size_t)s*HD+lane+64];
    float s0 = sinb[(size_t)s*HD+lane], s1 = sinb[(size_t)s*HD+lane+64];
    float o0 = y0*c0 - y1*s0;
    float o1 = y1*c1 + y0*s1;
    float sc = (slot < 32) ? (ATT_SCALE*LOG2E) : 1.0f;
    u16* dst = (slot < 32) ? (Qn + ((size_t)slot*S_LEN + s)*HD)
                           : (Kn + ((size_t)(slot-32)*S_LEN + s)*HD);
    dst[lane]    = (u16)f2bfbits(o0*sc);
    dst[lane+64] = (u16)f2bfbits(o1*sc);
  } else {
    int kvh = slot - 40;
    u16* dst = Vt + (size_t)kvh*HD*S_LEN + s;
    dst[(size_t)lane*S_LEN]      = (u16)f2bfbits(x0);
    dst[(size_t)(lane+64)*S_LEN] = (u16)f2bfbits(x1);
  }
}

// ---------------- flash attention v5 (causal, GQA, balanced) ----------------
// Scores arrive in log2 domain (LOG2E folded into Q): exp2f direct.
// K-stage before QK^T, V-stage after QK^T (spread vmem issue; both guarded
// by the loop-end __syncthreads vmcnt drain). setprio around MFMA clusters.
__global__ __launch_bounds__(256) void flash_attn(const u16* __restrict__ Qn,
                                                  const u16* __restrict__ Kn,
                                                  const u16* __restrict__ Vt,
                                                  u16* __restrict__ O){
  __shared__ u16 Ks[2][64*128];   // [kv][d] swizzled, 16KB each
  __shared__ u16 Vs[2][128*64];   // [d][kv] swizzled, 16KB each

  const int h = blockIdx.y;
  const int w = threadIdx.x>>6, lane = threadIdx.x&63, ln = lane&15, g = lane>>4;
  const int kvh = h>>2;                        // NH/NKV = 4
  const u16* Qh = Qn + (size_t)h*S_LEN*HD;
  const u16* Kh = Kn + (size_t)kvh*S_LEN*HD;
  const u16* Vh = Vt + (size_t)kvh*HD*S_LEN;

  const int krow_w = w*4 + g;
  const int ksw    = ((krow_w)&7)<<4;
  const int kcol   = ((ln*16) ^ ksw) >> 1;
  const int vrow_w = w*8 + (lane>>3);
  const int vsw    = ((lane>>3)&7)<<4;
  const int vcol   = (((lane&7)*16) ^ vsw) >> 1;

  #define STAGE_K(bufi, t) { \
    int kv0_ = (t)*64; \
    _Pragma("unroll") \
    for (int p=0;p<4;p++){ \
      const u16* ga = Kh + (size_t)(kv0_ + p*16 + krow_w)*HD + kcol; \
      GLOAD16(ga, (char*)&Ks[bufi][0] + p*4096 + w*1024); \
    } \
  }
  #define STAGE_V(bufi, t) { \
    int kv0_ = (t)*64; \
    _Pragma("unroll") \
    for (int p=0;p<4;p++){ \
      const u16* gv = Vh + (size_t)(p*32 + vrow_w)*S_LEN + kv0_ + vcol; \
      GLOAD16(gv, (char*)&Vs[bufi][0] + p*4096 + w*1024); \
    } \
  }

  #pragma unroll 1
  for (int ph=0; ph<2; ph++){
    const int qb = ph ? (31 - blockIdx.x) : blockIdx.x;
    const int q0 = qb*64;
    const int qrow = q0 + w*16 + ln;

    short8 qf[4];
    #pragma unroll
    for (int c=0;c<4;c++)
      qf[c] = *(const short8*)(Qh + (size_t)qrow*HD + c*32 + g*8);

    f32x4 ot[8];
    #pragma unroll
    for (int dt=0;dt<8;dt++) ot[dt] = (f32x4){0.f,0.f,0.f,0.f};
    float m_run = -1e30f, l_run = 0.f;

    const int nt = qb + 1;

    STAGE_K(0, 0); STAGE_V(0, 0);
    __syncthreads();

    for (int t=0; t<nt; ++t){
      const int cur = t&1;
      if (t+1 < nt) STAGE_K(cur^1, t+1);
      const int kv0 = t*64;

      // QK^T: S^T[kv][q] tiles, A = K from LDS, B = qf
      f32x4 st[4];
      #pragma unroll
      for (int mt=0; mt<4; mt++){
        short8 kf[4];
        #pragma unroll
        for (int c=0;c<4;c++)
          kf[c] = *(const short8*)((const char*)&Ks[cur][0]
                      + (mt*16+ln)*256 + ((c*64 + g*16) ^ ((ln&7)<<4)));
        f32x4 acc = (f32x4){0.f,0.f,0.f,0.f};
        __builtin_amdgcn_s_setprio(1);
        #pragma unroll
        for (int c=0;c<4;c++)
          acc = __builtin_amdgcn_mfma_f32_16x16x32_bf16(kf[c], qf[c], acc, 0,0,0);
        __builtin_amdgcn_s_setprio(0);
        st[mt] = acc;
      }

      if (t+1 < nt) STAGE_V(cur^1, t+1);

      // softmax in log2 domain (per-lane row stats, q = ln)
      float p[4][4];
      float mtile = -1e30f;
      if (t < qb){
        #pragma unroll
        for (int mt=0; mt<4; mt++)
          #pragma unroll
          for (int r=0;r<4;r++){
            p[mt][r] = st[mt][r];
            mtile = fmaxf(mtile, st[mt][r]);
          }
      } else {
        #pragma unroll
        for (int mt=0; mt<4; mt++)
          #pragma unroll
          for (int r=0;r<4;r++){
            int kv = kv0 + mt*16 + 4*g + r;
            float sv = (kv <= qrow) ? st[mt][r] : -1e30f;
            p[mt][r] = sv;
            mtile = fmaxf(mtile, sv);
          }
      }
      mtile = fmaxf(mtile, __shfl_xor(mtile, 16, 64));
      mtile = fmaxf(mtile, __shfl_xor(mtile, 32, 64));

      // defer-max: THR = 8 nats = 11.5416 in log2 domain
      bool defer = __all(mtile <= m_run + 11.5416f);
      float m_new = defer ? m_run : fmaxf(m_run, mtile);

      float l_tile = 0.f;
      #pragma unroll
      for (int mt=0; mt<4; mt++)
        #pragma unroll
        for (int r=0;r<4;r++){
          float e = exp2f(p[mt][r] - m_new);
          p[mt][r] = e;
          l_tile += e;
        }
      l_tile += __shfl_xor(l_tile, 16, 64);
      l_tile += __shfl_xor(l_tile, 32, 64);
      if (defer){
        l_run += l_tile;
      } else {
        float alpha = exp2f(m_run - m_new);
        l_run = l_run*alpha + l_tile;
        m_run = m_new;
        #pragma unroll
        for (int dt=0;dt<8;dt++) ot[dt] *= alpha;
      }

      // P redistribution per 32-kv half (cvt_pk packing, shfl recipe)
      short8 pf[2];
      #pragma unroll
      for (int ks2=0; ks2<2; ks2++){
        unsigned pk00 = cvtpk(p[2*ks2  ][0], p[2*ks2  ][1]);
        unsigned pk01 = cvtpk(p[2*ks2  ][2], p[2*ks2  ][3]);
        unsigned pk10 = cvtpk(p[2*ks2+1][0], p[2*ks2+1][1]);
        unsigned pk11 = cvtpk(p[2*ks2+1][2], p[2*ks2+1][3]);
        int src0 = (((2*g  )&3)<<4) | ln;
        int src1 = (((2*g+1)&3)<<4) | ln;
        unsigned t00 = (unsigned)__shfl((int)pk00, src0, 64);
        unsigned t10 = (unsigned)__shfl((int)pk10, src0, 64);
        unsigned t01 = (unsigned)__shfl((int)pk01, src0, 64);
        unsigned t11 = (unsigned)__shfl((int)pk11, src0, 64);
        unsigned u00 = (unsigned)__shfl((int)pk00, src1, 64);
        unsigned u10 = (unsigned)__shfl((int)pk10, src1, 64);
        unsigned u01 = (unsigned)__shfl((int)pk01, src1, 64);
        unsigned u11 = (unsigned)__shfl((int)pk11, src1, 64);
        bool hiv = (g >= 2);
        union { unsigned u[4]; short8 s; } pw;
        pw.u[0] = hiv ? t10 : t00;
        pw.u[1] = hiv ? t11 : t01;
        pw.u[2] = hiv ? u10 : u00;
        pw.u[3] = hiv ? u11 : u01;
        pf[ks2] = pw.s;
      }

      // PV: O^T[d][q] += V^T chunks * P^T, A = V from LDS
      #pragma unroll
      for (int dt=0;dt<8;dt++){
        short8 vf[2];
        #pragma unroll
        for (int ks2=0; ks2<2; ks2++)
          vf[ks2] = *(const short8*)((const char*)&Vs[cur][0]
                      + (dt*16+ln)*128 + ((ks2*64 + g*16) ^ ((ln&7)<<4)));
        __builtin_amdgcn_s_setprio(1);
        #pragma unroll
        for (int ks2=0; ks2<2; ks2++)
          ot[dt] = __builtin_amdgcn_mfma_f32_16x16x32_bf16(vf[ks2], pf[ks2], ot[dt], 0,0,0);
        __builtin_amdgcn_s_setprio(0);
      }
      __syncthreads();
    }

    float inv = 1.0f / l_run;
    u16* orow = O + (size_t)qrow*(NH*HD) + h*HD;
    #pragma unroll
    for (int dt=0;dt<8;dt++){
      #pragma unroll
      for (int rr=0; rr<4; rr+=2){
        unsigned pkd = cvtpk(ot[dt][rr]*inv, ot[dt][rr+1]*inv);
        *(unsigned*)(orow + dt*16 + g*4 + rr) = pkd;
      }
    }
  }
  #undef STAGE_K
  #undef STAGE_V
}

// ---------------- host ----------------
extern "C" void kernel_launch(void* const* d_in, const int* in_sizes, int n_in,
                              void* d_out, int out_size, void* d_ws, size_t ws_size,
                              hipStream_t stream){
  (void)in_sizes; (void)n_in; (void)out_size; (void)ws_size;
  const float* hs   = (const float*)d_in[0];
  const float* cosb = (const float*)d_in[1];
  const float* sinb = (const float*)d_in[2];
  const float* Wq   = (const float*)d_in[3];
  const float* Wk   = (const float*)d_in[4];
  const float* Wv   = (const float*)d_in[5];
  const float* Wo   = (const float*)d_in[6];
  const float* qw   = (const float*)d_in[7];
  const float* kw   = (const float*)d_in[8];
  float* out = (float*)d_out;

  char* ws = (char*)d_ws;
  u16*   Xb    = (u16*)  (ws);
  u16*   WQKV  = (u16*)  (ws + 16777216);
  u16*   QKVb  = (u16*)  (ws + 67108864);   // bf16 QKV (24 MiB)
  u16*   attnB = (u16*)  (ws + 94371840);   // separate region (16 MiB)
  u16*   Qn    = (u16*)  (ws + 117440512);
  u16*   Kn    = (u16*)  (ws + 134217728);
  u16*   Vt    = (u16*)  (ws + 138412032);
  u16*   Wob   = WQKV;                      // overlay: WQKV dead after GEMM1

  // 1. convert X + Wq|Wk|Wv in one launch (4 segments)
  cvt_all<<<dim3(8192, 4), 256, 0, stream>>>(hs, Wq, Wk, Wv, Xb, WQKV);
  // 2. GEMM1: [2048 x 4096] x [6144 x 4096]^T -> bf16 QKV, 256 blocks
  gemm_4ph<256,192,u16><<<256, 512, 0, stream>>>(Xb, WQKV, QKVb, NQKV, HIDD, NQKV/192);
  // 3. RMSNorm + RoPE + relayout (bf16 in)
  norm_rope<<<(S_LEN*48)/4, 256, 0, stream>>>(QKVb, cosb, sinb, qw, kw, Qn, Kn, Vt);
  // 4. convert Wo into the now-dead WQKV region
  cvt_bf16<<<(HIDD*NH*HD/8)/256, 256, 0, stream>>>(Wo, Wob, HIDD*NH*HD/8);
  // 5. flash attention: 16 complementary pairs x 32 heads = 512 blocks
  flash_attn<<<dim3(16, NH), 256, 0, stream>>>(Qn, Kn, Vt, attnB);
  // 6. GEMM2: [2048 x 4096] x [4096 x 4096]^T -> fp32 out, 256 blocks
  gemm_4ph<128,256,float><<<256, 512, 0, stream>>>(attnB, Wob, out, HIDD, HIDD, HIDD/256);
}